// Round 5
// baseline (1227.568 us; speedup 1.0000x reference)
//
#include <hip/hip_runtime.h>

#define N_NODESC 100000
#define N_EDGESC 1600000
#define BN_EPSC 1e-5f
#define NBUCK 1024              // coarse buckets (dst>>7, 128 nodes each), 782 used
#define NUSED 782               // ceil(100000/128)
#define SBLK 256                // castsort blocks
#define EPB (N_EDGESC / SBLK)   // 6250 edges per block
#define MT 128                  // nodes per MLP block
#define BCAPG 2304              // global per-bucket stride (mean 1562, ~18 sigma)

// ---------------------------------------------------------------------------
// K_castsort: ONE preprocessing kernel.  (unchanged)
// packed = src(17b) | attr<<17(2b) | (dst&127)<<19(7b).
// ---------------------------------------------------------------------------
__global__ __launch_bounds__(1024) void k_castsort(
    const int* __restrict__ ei, const int* __restrict__ ea,
    const float* __restrict__ x, uint2* __restrict__ xh4,
    int* __restrict__ gcur, int* __restrict__ tmp)
{
    __shared__ int ledge[EPB + 22];     // 6272 sorted packed edges
    __shared__ int cnt[NBUCK];
    __shared__ int cstart[NBUCK + 1];
    __shared__ int cur[NBUCK];
    __shared__ int gofs[NBUCK];
    __shared__ int wtot[16];
    const int t = threadIdx.x;
    const int k = blockIdx.x;

    cnt[t] = 0;
    {   // ---- bf16 cast, batched ----
        const float4* x4 = (const float4*)x;
        const int g = k * 1024 + t;
        float4 v[7];
        bool m[7];
        #pragma unroll
        for (int i = 0; i < 7; i++) {
            const int idx = g + i * (SBLK * 1024);
            m[i] = (idx < N_NODESC * 16);
            if (m[i]) v[i] = x4[idx];
        }
        #pragma unroll
        for (int i = 0; i < 7; i++) {
            if (m[i]) {
                const int idx = g + i * (SBLK * 1024);
                unsigned int a = __float_as_uint(v[i].x);
                unsigned int b = __float_as_uint(v[i].y);
                unsigned int c = __float_as_uint(v[i].z);
                unsigned int d = __float_as_uint(v[i].w);
                a = (a + 0x7FFFu + ((a >> 16) & 1u)) >> 16;
                b = (b + 0x7FFFu + ((b >> 16) & 1u)) >> 16;
                c = (c + 0x7FFFu + ((c >> 16) & 1u)) >> 16;
                d = (d + 0x7FFFu + ((d >> 16) & 1u)) >> 16;
                xh4[idx] = make_uint2(a | (b << 16), c | (d << 16));
            }
        }
    }
    __syncthreads();        // cnt zeroed before counting

    int pk[7], bk[7];
    const int base = k * EPB;
    #pragma unroll
    for (int i = 0; i < 7; i++) {
        const int e = base + i * 1024 + t;
        if (e < base + EPB) {
            const int src = ei[e];
            const int dst = ei[N_EDGESC + e];
            const int a = ea[e];
            pk[i] = src | (a << 17) | ((dst & 127) << 19);
            bk[i] = dst >> 7;
            atomicAdd(&cnt[bk[i]], 1);
        } else bk[i] = -1;
    }
    __syncthreads();

    {   // exclusive scan of 1024 counts
        const int lane = t & 63;
        const int w = t >> 6;
        const int v = cnt[t];
        int inc = v;
        #pragma unroll
        for (int d = 1; d < 64; d <<= 1) {
            const int u = __shfl_up(inc, d);
            if (lane >= d) inc += u;
        }
        if (lane == 63) wtot[w] = inc;
        __syncthreads();
        int add = 0;
        #pragma unroll
        for (int w2 = 0; w2 < 16; w2++) if (w2 < w) add += wtot[w2];
        const int ex = inc - v + add;
        cstart[t] = ex;
        cur[t] = ex;
        if (t == 1023) cstart[NBUCK] = ex + v;
    }
    __syncthreads();

    #pragma unroll
    for (int i = 0; i < 7; i++) {
        if (bk[i] >= 0) {
            const int pos = atomicAdd(&cur[bk[i]], 1);
            ledge[pos] = pk[i];
        }
    }
    {
        const int c = cnt[t];
        if (c > 0) gofs[t] = atomicAdd(&gcur[t], c);
    }
    __syncthreads();

    for (int i = t; i < EPB; i += 1024) {
        int lo = 0, hi = NBUCK;
        #pragma unroll
        for (int s = 0; s < 10; s++) {
            const int mid = (lo + hi) >> 1;
            if (cstart[mid] <= i) lo = mid; else hi = mid;
        }
        const int o = gofs[lo] + (i - cstart[lo]);
        if (o < BCAPG) tmp[lo * BCAPG + o] = ledge[i];
    }
}

// ---------------------------------------------------------------------------
// K_aggmlp1 v3 — barrier-free fusion, shfl-broadcast GEMM.
//  R4 lesson: 64 accumulators/lane (p[16] float4) -> 256 VGPR + scratch
//  spill (FETCH 697MB). Fix: transpose the GEMM work split. Each lane owns
//  its 8 OUTPUT columns (A0/A1 per node); the k-dimension values come from
//  the 8-lane group via __shfl(h[j][kk], l, 8) broadcasts. W-reads amortized
//  over the group's 4 nodes in one k-loop: per k = 2 ds_read_b128
//  (conflict-free: 8 distinct addrs x 8-lane broadcast) + 4 shfl + 32 FMA.
//  Totals/thread: 128 W-reads, 256 shfl, 2048 FMA — hides under the
//  fabric-bound gather (R1/R2: ~2.7TB/s regardless of occupancy).
//  NO barrier after the sort; waves flow gather->GEMM independently.
//  h[4][8], A0[4], A1[4] all statically indexed (rule #20).
//  __launch_bounds__(256,4) caps VGPR at 128 => spill impossible by
//  construction, 16 waves/CU, all 782 blocks co-resident.
// ---------------------------------------------------------------------------
__global__ __launch_bounds__(256, 4) void k_aggmlp1(
    const ushort* __restrict__ xh, const float* __restrict__ emb,
    const float* __restrict__ x, const float* __restrict__ epsp,
    const int* __restrict__ gcur, const int* __restrict__ tmp,
    const float* __restrict__ W1, const float* __restrict__ b1,
    float* __restrict__ out, float* __restrict__ cs, float* __restrict__ css)
{
    __shared__ int packedL[BCAPG];      // 9216B
    __shared__ int cnt[128];
    __shared__ int cst[128];
    __shared__ int cur[128];
    __shared__ float emL[4][68];        // padded edge-emb table
    __shared__ float lW[4096];          // 16384B: W1 k-major (16 float4/row)
    const int t = threadIdx.x;
    const int b = blockIdx.x;
    const int start = b * BCAPG;

    {   // ---- stage W1 (linear; latency hides under the sort) ----
        const float4* W4 = (const float4*)W1;
        float4* lw4 = (float4*)lW;
        #pragma unroll
        for (int i = 0; i < 4; i++) lw4[i * 256 + t] = W4[i * 256 + t];
    }
    int cntb = gcur[b];
    if (cntb > BCAPG) cntb = BCAPG;
    if (t < 128) cnt[t] = 0;
    emL[t >> 6][t & 63] = emb[t];
    __syncthreads();

    // pass 1: per-node counts
    for (int e = t; e < cntb; e += 256)
        atomicAdd(&cnt[(tmp[start + e] >> 19) & 127], 1);
    __syncthreads();
    if (t < 64) {   // scan 128 counts (two 64-lane halves)
        const int lane = t;
        const int v0 = cnt[lane];
        const int v1 = cnt[64 + lane];
        int i0 = v0, i1 = v1;
        #pragma unroll
        for (int d = 1; d < 64; d <<= 1) {
            const int u0 = __shfl_up(i0, d);
            const int u1 = __shfl_up(i1, d);
            if (lane >= d) { i0 += u0; i1 += u1; }
        }
        const int tot0 = __shfl(i0, 63);
        cst[lane] = i0 - v0;
        cst[64 + lane] = tot0 + i1 - v1;
        cur[lane] = i0 - v0;
        cur[64 + lane] = tot0 + i1 - v1;
    }
    __syncthreads();
    // pass 2: place node-sorted into LDS
    for (int e = t; e < cntb; e += 256) {
        const int p = tmp[start + e];
        const int pos = atomicAdd(&cur[(p >> 19) & 127], 1);
        if (pos < BCAPG) packedL[pos] = p;
    }
    __syncthreads();    // LAST barrier — everything below is wave-local

    // ---- group g owns nodes g*4..g*4+3; lane q = feature octet ----------
    const int g = t >> 3;                // 0..31
    const int q = t & 7;                 // features [q*8, q*8+8)
    const float sc1 = 1.0f + epsp[0];
    const uint4* xv8 = (const uint4*)xh;
    const float4* x4 = (const float4*)x;
    float4* o4 = (float4*)out;
    const float* eq = &emL[0][0] + q * 8;

    // ---- phase A: gather h_pre for 4 nodes into registers ---------------
    float h[4][8];
    #pragma unroll
    for (int j = 0; j < 4; j++) {
        const int nl = g * 4 + j;
        const int n = b * 128 + nl;
        int e = cst[nl];
        const int ee = cur[nl];           // cur == end after pass 2
        float4 aL = make_float4(0.f, 0.f, 0.f, 0.f);
        float4 aH = make_float4(0.f, 0.f, 0.f, 0.f);
        if (n < N_NODESC) {
            const float4 v0 = x4[(size_t)n * 16 + q * 2];
            const float4 v1 = x4[(size_t)n * 16 + q * 2 + 1];
            aL.x = sc1 * v0.x; aL.y = sc1 * v0.y;
            aL.z = sc1 * v0.z; aL.w = sc1 * v0.w;
            aH.x = sc1 * v1.x; aH.y = sc1 * v1.y;
            aH.z = sc1 * v1.z; aH.w = sc1 * v1.w;
        }
        for (; e + 2 <= ee; e += 2) {
            const int p0 = packedL[e];
            const int p1 = packedL[e + 1];
            const uint4 u0 = xv8[(size_t)(p0 & 0x1FFFF) * 8 + q];
            const uint4 u1 = xv8[(size_t)(p1 & 0x1FFFF) * 8 + q];
            const float* e0 = eq + ((p0 >> 17) & 3) * 68;
            const float* e1 = eq + ((p1 >> 17) & 3) * 68;
            const float4 t0L = *(const float4*)(e0);
            const float4 t0H = *(const float4*)(e0 + 4);
            const float4 t1L = *(const float4*)(e1);
            const float4 t1H = *(const float4*)(e1 + 4);
            aL.x += fmaxf(__uint_as_float(u0.x << 16)          + t0L.x, 0.f)
                  + fmaxf(__uint_as_float(u1.x << 16)          + t1L.x, 0.f);
            aL.y += fmaxf(__uint_as_float(u0.x & 0xFFFF0000u)  + t0L.y, 0.f)
                  + fmaxf(__uint_as_float(u1.x & 0xFFFF0000u)  + t1L.y, 0.f);
            aL.z += fmaxf(__uint_as_float(u0.y << 16)          + t0L.z, 0.f)
                  + fmaxf(__uint_as_float(u1.y << 16)          + t1L.z, 0.f);
            aL.w += fmaxf(__uint_as_float(u0.y & 0xFFFF0000u)  + t0L.w, 0.f)
                  + fmaxf(__uint_as_float(u1.y & 0xFFFF0000u)  + t1L.w, 0.f);
            aH.x += fmaxf(__uint_as_float(u0.z << 16)          + t0H.x, 0.f)
                  + fmaxf(__uint_as_float(u1.z << 16)          + t1H.x, 0.f);
            aH.y += fmaxf(__uint_as_float(u0.z & 0xFFFF0000u)  + t0H.y, 0.f)
                  + fmaxf(__uint_as_float(u1.z & 0xFFFF0000u)  + t1H.y, 0.f);
            aH.z += fmaxf(__uint_as_float(u0.w << 16)          + t0H.z, 0.f)
                  + fmaxf(__uint_as_float(u1.w << 16)          + t1H.z, 0.f);
            aH.w += fmaxf(__uint_as_float(u0.w & 0xFFFF0000u)  + t0H.w, 0.f)
                  + fmaxf(__uint_as_float(u1.w & 0xFFFF0000u)  + t1H.w, 0.f);
        }
        for (; e < ee; e++) {
            const int p0 = packedL[e];
            const uint4 u0 = xv8[(size_t)(p0 & 0x1FFFF) * 8 + q];
            const float* e0 = eq + ((p0 >> 17) & 3) * 68;
            const float4 t0L = *(const float4*)(e0);
            const float4 t0H = *(const float4*)(e0 + 4);
            aL.x += fmaxf(__uint_as_float(u0.x << 16)         + t0L.x, 0.f);
            aL.y += fmaxf(__uint_as_float(u0.x & 0xFFFF0000u) + t0L.y, 0.f);
            aL.z += fmaxf(__uint_as_float(u0.y << 16)         + t0L.z, 0.f);
            aL.w += fmaxf(__uint_as_float(u0.y & 0xFFFF0000u) + t0L.w, 0.f);
            aH.x += fmaxf(__uint_as_float(u0.z << 16)         + t0H.x, 0.f);
            aH.y += fmaxf(__uint_as_float(u0.z & 0xFFFF0000u) + t0H.y, 0.f);
            aH.z += fmaxf(__uint_as_float(u0.w << 16)         + t0H.z, 0.f);
            aH.w += fmaxf(__uint_as_float(u0.w & 0xFFFF0000u) + t0H.w, 0.f);
        }
        h[j][0] = aL.x; h[j][1] = aL.y; h[j][2] = aL.z; h[j][3] = aL.w;
        h[j][4] = aH.x; h[j][5] = aH.y; h[j][6] = aH.z; h[j][7] = aH.w;
    }

    // ---- phase B: GEMM, lane q computes cols q*8..q*8+7 for 4 nodes -----
    const float4* lw4r = (const float4*)lW;
    const float4* b4 = (const float4*)b1;
    const float4 bb0 = b4[q * 2 + 0];
    const float4 bb1 = b4[q * 2 + 1];
    float4 A0[4], A1[4];
    #pragma unroll
    for (int j = 0; j < 4; j++) { A0[j] = bb0; A1[j] = bb1; }
    #pragma unroll
    for (int l = 0; l < 8; l++) {
        #pragma unroll
        for (int kk = 0; kk < 8; kk++) {
            const int k = l * 8 + kk;
            const float4 w0 = lw4r[k * 16 + q * 2 + 0];
            const float4 w1 = lw4r[k * 16 + q * 2 + 1];
            const float hv0 = __shfl(h[0][kk], l, 8);
            const float hv1 = __shfl(h[1][kk], l, 8);
            const float hv2 = __shfl(h[2][kk], l, 8);
            const float hv3 = __shfl(h[3][kk], l, 8);
            A0[0].x = fmaf(hv0, w0.x, A0[0].x); A0[0].y = fmaf(hv0, w0.y, A0[0].y);
            A0[0].z = fmaf(hv0, w0.z, A0[0].z); A0[0].w = fmaf(hv0, w0.w, A0[0].w);
            A1[0].x = fmaf(hv0, w1.x, A1[0].x); A1[0].y = fmaf(hv0, w1.y, A1[0].y);
            A1[0].z = fmaf(hv0, w1.z, A1[0].z); A1[0].w = fmaf(hv0, w1.w, A1[0].w);
            A0[1].x = fmaf(hv1, w0.x, A0[1].x); A0[1].y = fmaf(hv1, w0.y, A0[1].y);
            A0[1].z = fmaf(hv1, w0.z, A0[1].z); A0[1].w = fmaf(hv1, w0.w, A0[1].w);
            A1[1].x = fmaf(hv1, w1.x, A1[1].x); A1[1].y = fmaf(hv1, w1.y, A1[1].y);
            A1[1].z = fmaf(hv1, w1.z, A1[1].z); A1[1].w = fmaf(hv1, w1.w, A1[1].w);
            A0[2].x = fmaf(hv2, w0.x, A0[2].x); A0[2].y = fmaf(hv2, w0.y, A0[2].y);
            A0[2].z = fmaf(hv2, w0.z, A0[2].z); A0[2].w = fmaf(hv2, w0.w, A0[2].w);
            A1[2].x = fmaf(hv2, w1.x, A1[2].x); A1[2].y = fmaf(hv2, w1.y, A1[2].y);
            A1[2].z = fmaf(hv2, w1.z, A1[2].z); A1[2].w = fmaf(hv2, w1.w, A1[2].w);
            A0[3].x = fmaf(hv3, w0.x, A0[3].x); A0[3].y = fmaf(hv3, w0.y, A0[3].y);
            A0[3].z = fmaf(hv3, w0.z, A0[3].z); A0[3].w = fmaf(hv3, w0.w, A0[3].w);
            A1[3].x = fmaf(hv3, w1.x, A1[3].x); A1[3].y = fmaf(hv3, w1.y, A1[3].y);
            A1[3].z = fmaf(hv3, w1.z, A1[3].z); A1[3].w = fmaf(hv3, w1.w, A1[3].w);
        }
    }

    // ---- store h1 + BN partial sums -------------------------------------
    float vs[8], vq[8];
    #pragma unroll
    for (int c = 0; c < 8; c++) { vs[c] = 0.f; vq[c] = 0.f; }
    #pragma unroll
    for (int j = 0; j < 4; j++) {
        const int n = b * 128 + g * 4 + j;
        const float mk = (n < N_NODESC) ? 1.0f : 0.0f;
        if (n < N_NODESC) {
            o4[(size_t)n * 16 + q * 2 + 0] = A0[j];
            o4[(size_t)n * 16 + q * 2 + 1] = A1[j];
        }
        const float h8[8] = {A0[j].x, A0[j].y, A0[j].z, A0[j].w,
                             A1[j].x, A1[j].y, A1[j].z, A1[j].w};
        #pragma unroll
        for (int c = 0; c < 8; c++) {
            const float v = h8[c] * mk;
            vs[c] += v;
            vq[c] += v * h8[c];
        }
    }
    #pragma unroll
    for (int m = 8; m < 64; m <<= 1) {
        #pragma unroll
        for (int c = 0; c < 8; c++) {
            vs[c] += __shfl_xor(vs[c], m);
            vq[c] += __shfl_xor(vq[c], m);
        }
    }
    if ((t & 63) < 8) {
        #pragma unroll
        for (int c = 0; c < 8; c++) {
            unsafeAtomicAdd(&cs[q * 8 + c], vs[c]);
            unsafeAtomicAdd(&css[q * 8 + c], vq[c]);
        }
    }
}

// ---------------------------------------------------------------------------
// K_mlp2: out = relu(BN(h1)) @ W2 + b2.  h1 aliases out; LDS-staged.
// ---------------------------------------------------------------------------
__global__ __launch_bounds__(256) void k_mlp2(
    const float* h1, const float* __restrict__ W2, const float* __restrict__ b2,
    const float* __restrict__ gamma, const float* __restrict__ beta,
    const float* __restrict__ cs, const float* __restrict__ css,
    float* out)
{
    __shared__ float lin[MT][68];
    __shared__ float lW[4096];
    __shared__ float scl[64];
    __shared__ float sft[64];
    const int t = threadIdx.x;
    const int nbase = blockIdx.x * MT;

    if (t < 64) {
        const float inv = 1.0f / (float)N_NODESC;
        const float mu = cs[t] * inv;
        const float var = css[t] * inv - mu * mu;
        const float rs = rsqrtf(var + BN_EPSC);
        const float s = rs * gamma[t];
        scl[t] = s;
        sft[t] = fmaf(-mu, s, beta[t]);
    }
    {
        const float4* W4 = (const float4*)W2;
        float4* lW4 = (float4*)lW;
        #pragma unroll
        for (int i = 0; i < 4; i++) lW4[i * 256 + t] = W4[i * 256 + t];
    }
    __syncthreads();
    {
        const float4* h4 = (const float4*)h1;
        #pragma unroll
        for (int i = 0; i < 8; i++) {
            const int fidx = i * 256 + t;
            const int row = fidx >> 4;
            const int q = fidx & 15;
            const int n = nbase + row;
            float4 v = make_float4(0.f, 0.f, 0.f, 0.f);
            if (n < N_NODESC) {
                const float4 h = h4[(size_t)n * 16 + q];
                const int c = q * 4;
                v.x = fmaxf(fmaf(h.x, scl[c + 0], sft[c + 0]), 0.f);
                v.y = fmaxf(fmaf(h.y, scl[c + 1], sft[c + 1]), 0.f);
                v.z = fmaxf(fmaf(h.z, scl[c + 2], sft[c + 2]), 0.f);
                v.w = fmaxf(fmaf(h.w, scl[c + 3], sft[c + 3]), 0.f);
            }
            *(float4*)&lin[row][q * 4] = v;
        }
    }
    __syncthreads();

    const int g = t & 7;
    const int r0 = t >> 3;
    const float4* lW4 = (const float4*)lW;
    const float4* b4 = (const float4*)b2;
    const float4 bb0 = b4[g * 2 + 0];
    const float4 bb1 = b4[g * 2 + 1];
    float4 a00 = bb0, a01 = bb1, a10 = bb0, a11 = bb1;
    float4 a20 = bb0, a21 = bb1, a30 = bb0, a31 = bb1;
    for (int k = 0; k < 64; k++) {
        const float v0 = lin[r0][k];
        const float v1 = lin[r0 + 32][k];
        const float v2 = lin[r0 + 64][k];
        const float v3 = lin[r0 + 96][k];
        const float4 w0 = lW4[k * 16 + g * 2 + 0];
        const float4 w1 = lW4[k * 16 + g * 2 + 1];
        a00.x = fmaf(v0, w0.x, a00.x); a00.y = fmaf(v0, w0.y, a00.y);
        a00.z = fmaf(v0, w0.z, a00.z); a00.w = fmaf(v0, w0.w, a00.w);
        a01.x = fmaf(v0, w1.x, a01.x); a01.y = fmaf(v0, w1.y, a01.y);
        a01.z = fmaf(v0, w1.z, a01.z); a01.w = fmaf(v0, w1.w, a01.w);
        a10.x = fmaf(v1, w0.x, a10.x); a10.y = fmaf(v1, w0.y, a10.y);
        a10.z = fmaf(v1, w0.z, a10.z); a10.w = fmaf(v1, w0.w, a10.w);
        a11.x = fmaf(v1, w1.x, a11.x); a11.y = fmaf(v1, w1.y, a11.y);
        a11.z = fmaf(v1, w1.z, a11.z); a11.w = fmaf(v1, w1.w, a11.w);
        a20.x = fmaf(v2, w0.x, a20.x); a20.y = fmaf(v2, w0.y, a20.y);
        a20.z = fmaf(v2, w0.z, a20.z); a20.w = fmaf(v2, w0.w, a20.w);
        a21.x = fmaf(v2, w1.x, a21.x); a21.y = fmaf(v2, w1.y, a21.y);
        a21.z = fmaf(v2, w1.z, a21.z); a21.w = fmaf(v2, w1.w, a21.w);
        a30.x = fmaf(v3, w0.x, a30.x); a30.y = fmaf(v3, w0.y, a30.y);
        a30.z = fmaf(v3, w0.z, a30.z); a30.w = fmaf(v3, w0.w, a30.w);
        a31.x = fmaf(v3, w1.x, a31.x); a31.y = fmaf(v3, w1.y, a31.y);
        a31.z = fmaf(v3, w1.z, a31.z); a31.w = fmaf(v3, w1.w, a31.w);
    }
    const float4 A0[4] = {a00, a10, a20, a30};
    const float4 A1[4] = {a01, a11, a21, a31};
    float4* o4 = (float4*)out;
    #pragma unroll
    for (int j = 0; j < 4; j++) {
        const int n = nbase + r0 + 32 * j;
        if (n < N_NODESC) {
            o4[(size_t)n * 16 + g * 2 + 0] = A0[j];
            o4[(size_t)n * 16 + g * 2 + 1] = A1[j];
        }
    }
}

// ---------------------------------------------------------------------------
extern "C" void kernel_launch(void* const* d_in, const int* in_sizes, int n_in,
                              void* d_out, int out_size, void* d_ws, size_t ws_size,
                              hipStream_t stream) {
    const float* x     = (const float*)d_in[0];
    const float* emb   = (const float*)d_in[1];
    const float* eps   = (const float*)d_in[2];
    const float* W1    = (const float*)d_in[3];
    const float* b1    = (const float*)d_in[4];
    const float* gamma = (const float*)d_in[5];
    const float* beta  = (const float*)d_in[6];
    const float* W2    = (const float*)d_in[7];
    const float* b2    = (const float*)d_in[8];
    const int*   ei    = (const int*)d_in[9];
    const int*   ea    = (const int*)d_in[10];
    float* out = (float*)d_out;

    // ws: [cs 64][css 64][gcur NBUCK][tmp NBUCK*BCAPG][xh N*64 bf16]  (~22 MB)
    float* ws    = (float*)d_ws;
    float* cs    = ws;
    float* css   = ws + 64;
    int*   gcur  = (int*)(ws + 128);
    int*   tmp   = gcur + NBUCK;
    ushort* xh   = (ushort*)(tmp + (size_t)NBUCK * BCAPG);

    // zero cs/css/gcur (4.6 KB)
    hipMemsetAsync(d_ws, 0, (size_t)(128 + NBUCK) * sizeof(int), stream);

    k_castsort<<<SBLK, 1024, 0, stream>>>(ei, ea, x, (uint2*)xh, gcur, tmp);
    k_aggmlp1<<<NUSED, 256, 0, stream>>>(xh, emb, x, eps, gcur, tmp,
                                         W1, b1, out, cs, css);   // h1 -> d_out
    k_mlp2<<<NUSED, 256, 0, stream>>>(out, W2, b2, gamma, beta, cs, css, out);
}

// Round 6
// 780.491 us; speedup vs baseline: 1.5728x; 1.5728x over previous
//
#include <hip/hip_runtime.h>

#define N_NODESC 100000
#define N_EDGESC 1600000
#define BN_EPSC 1e-5f
#define NBUCK 1024              // coarse buckets (dst>>7, 128 nodes each), 782 used
#define NUSED 782               // ceil(100000/128)
#define SBLK 256                // castsort blocks
#define EPB (N_EDGESC / SBLK)   // 6250 edges per block
#define MT 128                  // nodes per MLP block
#define BCAPG 2304              // global per-bucket stride (mean 1562, ~18 sigma)

// ---------------------------------------------------------------------------
// K_castsort: ONE preprocessing kernel.  (unchanged)
// packed = src(17b) | attr<<17(2b) | (dst&127)<<19(7b).
// ---------------------------------------------------------------------------
__global__ __launch_bounds__(1024) void k_castsort(
    const int* __restrict__ ei, const int* __restrict__ ea,
    const float* __restrict__ x, uint2* __restrict__ xh4,
    int* __restrict__ gcur, int* __restrict__ tmp)
{
    __shared__ int ledge[EPB + 22];     // 6272 sorted packed edges
    __shared__ int cnt[NBUCK];
    __shared__ int cstart[NBUCK + 1];
    __shared__ int cur[NBUCK];
    __shared__ int gofs[NBUCK];
    __shared__ int wtot[16];
    const int t = threadIdx.x;
    const int k = blockIdx.x;

    cnt[t] = 0;
    {   // ---- bf16 cast, batched ----
        const float4* x4 = (const float4*)x;
        const int g = k * 1024 + t;
        float4 v[7];
        bool m[7];
        #pragma unroll
        for (int i = 0; i < 7; i++) {
            const int idx = g + i * (SBLK * 1024);
            m[i] = (idx < N_NODESC * 16);
            if (m[i]) v[i] = x4[idx];
        }
        #pragma unroll
        for (int i = 0; i < 7; i++) {
            if (m[i]) {
                const int idx = g + i * (SBLK * 1024);
                unsigned int a = __float_as_uint(v[i].x);
                unsigned int b = __float_as_uint(v[i].y);
                unsigned int c = __float_as_uint(v[i].z);
                unsigned int d = __float_as_uint(v[i].w);
                a = (a + 0x7FFFu + ((a >> 16) & 1u)) >> 16;
                b = (b + 0x7FFFu + ((b >> 16) & 1u)) >> 16;
                c = (c + 0x7FFFu + ((c >> 16) & 1u)) >> 16;
                d = (d + 0x7FFFu + ((d >> 16) & 1u)) >> 16;
                xh4[idx] = make_uint2(a | (b << 16), c | (d << 16));
            }
        }
    }
    __syncthreads();        // cnt zeroed before counting

    int pk[7], bk[7];
    const int base = k * EPB;
    #pragma unroll
    for (int i = 0; i < 7; i++) {
        const int e = base + i * 1024 + t;
        if (e < base + EPB) {
            const int src = ei[e];
            const int dst = ei[N_EDGESC + e];
            const int a = ea[e];
            pk[i] = src | (a << 17) | ((dst & 127) << 19);
            bk[i] = dst >> 7;
            atomicAdd(&cnt[bk[i]], 1);
        } else bk[i] = -1;
    }
    __syncthreads();

    {   // exclusive scan of 1024 counts
        const int lane = t & 63;
        const int w = t >> 6;
        const int v = cnt[t];
        int inc = v;
        #pragma unroll
        for (int d = 1; d < 64; d <<= 1) {
            const int u = __shfl_up(inc, d);
            if (lane >= d) inc += u;
        }
        if (lane == 63) wtot[w] = inc;
        __syncthreads();
        int add = 0;
        #pragma unroll
        for (int w2 = 0; w2 < 16; w2++) if (w2 < w) add += wtot[w2];
        const int ex = inc - v + add;
        cstart[t] = ex;
        cur[t] = ex;
        if (t == 1023) cstart[NBUCK] = ex + v;
    }
    __syncthreads();

    #pragma unroll
    for (int i = 0; i < 7; i++) {
        if (bk[i] >= 0) {
            const int pos = atomicAdd(&cur[bk[i]], 1);
            ledge[pos] = pk[i];
        }
    }
    {
        const int c = cnt[t];
        if (c > 0) gofs[t] = atomicAdd(&gcur[t], c);
    }
    __syncthreads();

    for (int i = t; i < EPB; i += 1024) {
        int lo = 0, hi = NBUCK;
        #pragma unroll
        for (int s = 0; s < 10; s++) {
            const int mid = (lo + hi) >> 1;
            if (cstart[mid] <= i) lo = mid; else hi = mid;
        }
        const int o = gofs[lo] + (i - cstart[lo]);
        if (o < BCAPG) tmp[lo * BCAPG + o] = ledge[i];
    }
}

// ---------------------------------------------------------------------------
// K_aggmlp1 v4 — wave-local LDS handoff, NO mid-kernel block barrier.
//  R4 lesson: 64 acc/lane -> 256 VGPR spill.  R5 lesson: h[4][8] live across
//  gather AND GEMM -> compiler spilled to scratch under launch_bounds cap
//  (FETCH 773MB).  Fix: NO per-lane state crosses the phase boundary.
//  Wave w's groups (g = t>>3 in [w*8, w*8+7]) own rows w*32..w*32+31; phase A
//  writes h_pre to lin[row][*] (R3's proven gather code verbatim), phase B
//  runs R3-mlp1's proven GEMM inner loop PER WAVE on its own 32-row subtile.
//  Same-wave LDS RAW is ordered by compiler lgkmcnt — no __syncthreads, so
//  waves drift: one wave's GEMM VALU overlaps other waves' gathers (the R3
//  convoy is gone), and register live ranges stay phase-local (no spill).
//  LDS 63KB -> 2 blocks/CU (8 waves); gather shown occupancy-insensitive in
//  this range (R0/R1).
// ---------------------------------------------------------------------------
__global__ __launch_bounds__(256) void k_aggmlp1(
    const ushort* __restrict__ xh, const float* __restrict__ emb,
    const float* __restrict__ x, const float* __restrict__ epsp,
    const int* __restrict__ gcur, const int* __restrict__ tmp,
    const float* __restrict__ W1, const float* __restrict__ b1,
    float* __restrict__ out, float* __restrict__ cs, float* __restrict__ css)
{
    __shared__ int packedL[BCAPG];      // 9216B
    __shared__ int cnt[128];
    __shared__ int cst[128];
    __shared__ int cur[128];
    __shared__ float emL[4][68];        // padded edge-emb table
    __shared__ float lW[4096];          // 16KB: W1 k-major (16 float4/row)
    __shared__ float lin[MT][68];       // 34816B: h_pre, wave-partitioned
    const int t = threadIdx.x;
    const int b = blockIdx.x;
    const int start = b * BCAPG;

    {   // ---- stage W1 (linear; latency hides under the sort) ----
        const float4* W4 = (const float4*)W1;
        float4* lw4 = (float4*)lW;
        #pragma unroll
        for (int i = 0; i < 4; i++) lw4[i * 256 + t] = W4[i * 256 + t];
    }
    int cntb = gcur[b];
    if (cntb > BCAPG) cntb = BCAPG;
    if (t < 128) cnt[t] = 0;
    emL[t >> 6][t & 63] = emb[t];
    __syncthreads();

    // pass 1: per-node counts
    for (int e = t; e < cntb; e += 256)
        atomicAdd(&cnt[(tmp[start + e] >> 19) & 127], 1);
    __syncthreads();
    if (t < 64) {   // scan 128 counts (two 64-lane halves)
        const int lane = t;
        const int v0 = cnt[lane];
        const int v1 = cnt[64 + lane];
        int i0 = v0, i1 = v1;
        #pragma unroll
        for (int d = 1; d < 64; d <<= 1) {
            const int u0 = __shfl_up(i0, d);
            const int u1 = __shfl_up(i1, d);
            if (lane >= d) { i0 += u0; i1 += u1; }
        }
        const int tot0 = __shfl(i0, 63);
        cst[lane] = i0 - v0;
        cst[64 + lane] = tot0 + i1 - v1;
        cur[lane] = i0 - v0;
        cur[64 + lane] = tot0 + i1 - v1;
    }
    __syncthreads();
    // pass 2: place node-sorted into LDS
    for (int e = t; e < cntb; e += 256) {
        const int p = tmp[start + e];
        const int pos = atomicAdd(&cur[(p >> 19) & 127], 1);
        if (pos < BCAPG) packedL[pos] = p;
    }
    __syncthreads();    // LAST block barrier — below is wave-local only

    // ---- phase A: gather; group g -> nodes g*4..g*4+3; lane q = octet ---
    {
        const int g = t >> 3;                // 0..31 (wave w: g in [8w,8w+7])
        const int q = t & 7;                 // features [q*8, q*8+8)
        const float sc1 = 1.0f + epsp[0];
        const uint4* xv8 = (const uint4*)xh;
        const float4* x4 = (const float4*)x;
        const float* eq = &emL[0][0] + q * 8;
        for (int j = 0; j < 4; j++) {
            const int nl = g * 4 + j;
            const int n = b * 128 + nl;
            int e = cst[nl];
            const int ee = cur[nl];           // cur == end after pass 2
            float4 aL = make_float4(0.f, 0.f, 0.f, 0.f);
            float4 aH = make_float4(0.f, 0.f, 0.f, 0.f);
            if (n < N_NODESC) {
                const float4 v0 = x4[(size_t)n * 16 + q * 2];
                const float4 v1 = x4[(size_t)n * 16 + q * 2 + 1];
                aL.x = sc1 * v0.x; aL.y = sc1 * v0.y;
                aL.z = sc1 * v0.z; aL.w = sc1 * v0.w;
                aH.x = sc1 * v1.x; aH.y = sc1 * v1.y;
                aH.z = sc1 * v1.z; aH.w = sc1 * v1.w;
            }
            for (; e + 2 <= ee; e += 2) {
                const int p0 = packedL[e];
                const int p1 = packedL[e + 1];
                const uint4 u0 = xv8[(size_t)(p0 & 0x1FFFF) * 8 + q];
                const uint4 u1 = xv8[(size_t)(p1 & 0x1FFFF) * 8 + q];
                const float* e0 = eq + ((p0 >> 17) & 3) * 68;
                const float* e1 = eq + ((p1 >> 17) & 3) * 68;
                const float4 t0L = *(const float4*)(e0);
                const float4 t0H = *(const float4*)(e0 + 4);
                const float4 t1L = *(const float4*)(e1);
                const float4 t1H = *(const float4*)(e1 + 4);
                aL.x += fmaxf(__uint_as_float(u0.x << 16)          + t0L.x, 0.f)
                      + fmaxf(__uint_as_float(u1.x << 16)          + t1L.x, 0.f);
                aL.y += fmaxf(__uint_as_float(u0.x & 0xFFFF0000u)  + t0L.y, 0.f)
                      + fmaxf(__uint_as_float(u1.x & 0xFFFF0000u)  + t1L.y, 0.f);
                aL.z += fmaxf(__uint_as_float(u0.y << 16)          + t0L.z, 0.f)
                      + fmaxf(__uint_as_float(u1.y << 16)          + t1L.z, 0.f);
                aL.w += fmaxf(__uint_as_float(u0.y & 0xFFFF0000u)  + t0L.w, 0.f)
                      + fmaxf(__uint_as_float(u1.y & 0xFFFF0000u)  + t1L.w, 0.f);
                aH.x += fmaxf(__uint_as_float(u0.z << 16)          + t0H.x, 0.f)
                      + fmaxf(__uint_as_float(u1.z << 16)          + t1H.x, 0.f);
                aH.y += fmaxf(__uint_as_float(u0.z & 0xFFFF0000u)  + t0H.y, 0.f)
                      + fmaxf(__uint_as_float(u1.z & 0xFFFF0000u)  + t1H.y, 0.f);
                aH.z += fmaxf(__uint_as_float(u0.w << 16)          + t0H.z, 0.f)
                      + fmaxf(__uint_as_float(u1.w << 16)          + t1H.z, 0.f);
                aH.w += fmaxf(__uint_as_float(u0.w & 0xFFFF0000u)  + t0H.w, 0.f)
                      + fmaxf(__uint_as_float(u1.w & 0xFFFF0000u)  + t1H.w, 0.f);
            }
            for (; e < ee; e++) {
                const int p0 = packedL[e];
                const uint4 u0 = xv8[(size_t)(p0 & 0x1FFFF) * 8 + q];
                const float* e0 = eq + ((p0 >> 17) & 3) * 68;
                const float4 t0L = *(const float4*)(e0);
                const float4 t0H = *(const float4*)(e0 + 4);
                aL.x += fmaxf(__uint_as_float(u0.x << 16)         + t0L.x, 0.f);
                aL.y += fmaxf(__uint_as_float(u0.x & 0xFFFF0000u) + t0L.y, 0.f);
                aL.z += fmaxf(__uint_as_float(u0.y << 16)         + t0L.z, 0.f);
                aL.w += fmaxf(__uint_as_float(u0.y & 0xFFFF0000u) + t0L.w, 0.f);
                aH.x += fmaxf(__uint_as_float(u0.z << 16)         + t0H.x, 0.f);
                aH.y += fmaxf(__uint_as_float(u0.z & 0xFFFF0000u) + t0H.y, 0.f);
                aH.z += fmaxf(__uint_as_float(u0.w << 16)         + t0H.z, 0.f);
                aH.w += fmaxf(__uint_as_float(u0.w & 0xFFFF0000u) + t0H.w, 0.f);
            }
            // h_pre -> this wave's LDS rows (own cells only)
            *(float4*)&lin[nl][q * 8]     = aL;
            *(float4*)&lin[nl][q * 8 + 4] = aH;
        }
    }
    // No barrier: wave w wrote rows w*32..w*32+31 and reads only those below;
    // same-wave ds_write->ds_read ordering is enforced by lgkmcnt.

    // ---- phase B (wave-local): h1 = lin @ W1 + b1 ; store; BN sums ------
    const int lane = t & 63;
    const int w = t >> 6;                // wave id 0..3
    const int gc = lane & 7;             // col group: cols [gc*8, gc*8+8)
    const int r0 = lane >> 3;            // 0..7
    const int rbase = w * 32 + r0;       // rows rbase + 8*m, m=0..3
    const float4* lW4r = (const float4*)lW;
    const float4* b4 = (const float4*)b1;
    const float4 bb0 = b4[gc * 2 + 0];
    const float4 bb1 = b4[gc * 2 + 1];
    float4 a00 = bb0, a01 = bb1, a10 = bb0, a11 = bb1;
    float4 a20 = bb0, a21 = bb1, a30 = bb0, a31 = bb1;
    for (int k = 0; k < 64; k++) {
        const float v0 = lin[rbase][k];
        const float v1 = lin[rbase + 8][k];
        const float v2 = lin[rbase + 16][k];
        const float v3 = lin[rbase + 24][k];
        const float4 w0 = lW4r[k * 16 + gc * 2 + 0];
        const float4 w1 = lW4r[k * 16 + gc * 2 + 1];
        a00.x = fmaf(v0, w0.x, a00.x); a00.y = fmaf(v0, w0.y, a00.y);
        a00.z = fmaf(v0, w0.z, a00.z); a00.w = fmaf(v0, w0.w, a00.w);
        a01.x = fmaf(v0, w1.x, a01.x); a01.y = fmaf(v0, w1.y, a01.y);
        a01.z = fmaf(v0, w1.z, a01.z); a01.w = fmaf(v0, w1.w, a01.w);
        a10.x = fmaf(v1, w0.x, a10.x); a10.y = fmaf(v1, w0.y, a10.y);
        a10.z = fmaf(v1, w0.z, a10.z); a10.w = fmaf(v1, w0.w, a10.w);
        a11.x = fmaf(v1, w1.x, a11.x); a11.y = fmaf(v1, w1.y, a11.y);
        a11.z = fmaf(v1, w1.z, a11.z); a11.w = fmaf(v1, w1.w, a11.w);
        a20.x = fmaf(v2, w0.x, a20.x); a20.y = fmaf(v2, w0.y, a20.y);
        a20.z = fmaf(v2, w0.z, a20.z); a20.w = fmaf(v2, w0.w, a20.w);
        a21.x = fmaf(v2, w1.x, a21.x); a21.y = fmaf(v2, w1.y, a21.y);
        a21.z = fmaf(v2, w1.z, a21.z); a21.w = fmaf(v2, w1.w, a21.w);
        a30.x = fmaf(v3, w0.x, a30.x); a30.y = fmaf(v3, w0.y, a30.y);
        a30.z = fmaf(v3, w0.z, a30.z); a30.w = fmaf(v3, w0.w, a30.w);
        a31.x = fmaf(v3, w1.x, a31.x); a31.y = fmaf(v3, w1.y, a31.y);
        a31.z = fmaf(v3, w1.z, a31.z); a31.w = fmaf(v3, w1.w, a31.w);
    }

    const float4 A0[4] = {a00, a10, a20, a30};
    const float4 A1[4] = {a01, a11, a21, a31};
    float4* o4 = (float4*)out;
    float vs[8], vq[8];
    #pragma unroll
    for (int c = 0; c < 8; c++) { vs[c] = 0.f; vq[c] = 0.f; }
    #pragma unroll
    for (int m = 0; m < 4; m++) {
        const int n = b * 128 + rbase + 8 * m;
        const float mk = (n < N_NODESC) ? 1.0f : 0.0f;
        if (n < N_NODESC) {
            o4[(size_t)n * 16 + gc * 2 + 0] = A0[m];
            o4[(size_t)n * 16 + gc * 2 + 1] = A1[m];
        }
        const float h8[8] = {A0[m].x, A0[m].y, A0[m].z, A0[m].w,
                             A1[m].x, A1[m].y, A1[m].z, A1[m].w};
        #pragma unroll
        for (int c = 0; c < 8; c++) {
            const float v = h8[c] * mk;
            vs[c] += v;
            vq[c] += v * h8[c];
        }
    }
    #pragma unroll
    for (int m = 8; m < 64; m <<= 1) {
        #pragma unroll
        for (int c = 0; c < 8; c++) {
            vs[c] += __shfl_xor(vs[c], m);
            vq[c] += __shfl_xor(vq[c], m);
        }
    }
    if (lane < 8) {     // lane == gc here
        #pragma unroll
        for (int c = 0; c < 8; c++) {
            unsafeAtomicAdd(&cs[gc * 8 + c], vs[c]);
            unsafeAtomicAdd(&css[gc * 8 + c], vq[c]);
        }
    }
}

// ---------------------------------------------------------------------------
// K_mlp2: out = relu(BN(h1)) @ W2 + b2.  h1 aliases out; LDS-staged.
// ---------------------------------------------------------------------------
__global__ __launch_bounds__(256) void k_mlp2(
    const float* h1, const float* __restrict__ W2, const float* __restrict__ b2,
    const float* __restrict__ gamma, const float* __restrict__ beta,
    const float* __restrict__ cs, const float* __restrict__ css,
    float* out)
{
    __shared__ float lin[MT][68];
    __shared__ float lW[4096];
    __shared__ float scl[64];
    __shared__ float sft[64];
    const int t = threadIdx.x;
    const int nbase = blockIdx.x * MT;

    if (t < 64) {
        const float inv = 1.0f / (float)N_NODESC;
        const float mu = cs[t] * inv;
        const float var = css[t] * inv - mu * mu;
        const float rs = rsqrtf(var + BN_EPSC);
        const float s = rs * gamma[t];
        scl[t] = s;
        sft[t] = fmaf(-mu, s, beta[t]);
    }
    {
        const float4* W4 = (const float4*)W2;
        float4* lW4 = (float4*)lW;
        #pragma unroll
        for (int i = 0; i < 4; i++) lW4[i * 256 + t] = W4[i * 256 + t];
    }
    __syncthreads();
    {
        const float4* h4 = (const float4*)h1;
        #pragma unroll
        for (int i = 0; i < 8; i++) {
            const int fidx = i * 256 + t;
            const int row = fidx >> 4;
            const int q = fidx & 15;
            const int n = nbase + row;
            float4 v = make_float4(0.f, 0.f, 0.f, 0.f);
            if (n < N_NODESC) {
                const float4 h = h4[(size_t)n * 16 + q];
                const int c = q * 4;
                v.x = fmaxf(fmaf(h.x, scl[c + 0], sft[c + 0]), 0.f);
                v.y = fmaxf(fmaf(h.y, scl[c + 1], sft[c + 1]), 0.f);
                v.z = fmaxf(fmaf(h.z, scl[c + 2], sft[c + 2]), 0.f);
                v.w = fmaxf(fmaf(h.w, scl[c + 3], sft[c + 3]), 0.f);
            }
            *(float4*)&lin[row][q * 4] = v;
        }
    }
    __syncthreads();

    const int g = t & 7;
    const int r0 = t >> 3;
    const float4* lW4 = (const float4*)lW;
    const float4* b4 = (const float4*)b2;
    const float4 bb0 = b4[g * 2 + 0];
    const float4 bb1 = b4[g * 2 + 1];
    float4 a00 = bb0, a01 = bb1, a10 = bb0, a11 = bb1;
    float4 a20 = bb0, a21 = bb1, a30 = bb0, a31 = bb1;
    for (int k = 0; k < 64; k++) {
        const float v0 = lin[r0][k];
        const float v1 = lin[r0 + 32][k];
        const float v2 = lin[r0 + 64][k];
        const float v3 = lin[r0 + 96][k];
        const float4 w0 = lW4[k * 16 + g * 2 + 0];
        const float4 w1 = lW4[k * 16 + g * 2 + 1];
        a00.x = fmaf(v0, w0.x, a00.x); a00.y = fmaf(v0, w0.y, a00.y);
        a00.z = fmaf(v0, w0.z, a00.z); a00.w = fmaf(v0, w0.w, a00.w);
        a01.x = fmaf(v0, w1.x, a01.x); a01.y = fmaf(v0, w1.y, a01.y);
        a01.z = fmaf(v0, w1.z, a01.z); a01.w = fmaf(v0, w1.w, a01.w);
        a10.x = fmaf(v1, w0.x, a10.x); a10.y = fmaf(v1, w0.y, a10.y);
        a10.z = fmaf(v1, w0.z, a10.z); a10.w = fmaf(v1, w0.w, a10.w);
        a11.x = fmaf(v1, w1.x, a11.x); a11.y = fmaf(v1, w1.y, a11.y);
        a11.z = fmaf(v1, w1.z, a11.z); a11.w = fmaf(v1, w1.w, a11.w);
        a20.x = fmaf(v2, w0.x, a20.x); a20.y = fmaf(v2, w0.y, a20.y);
        a20.z = fmaf(v2, w0.z, a20.z); a20.w = fmaf(v2, w0.w, a20.w);
        a21.x = fmaf(v2, w1.x, a21.x); a21.y = fmaf(v2, w1.y, a21.y);
        a21.z = fmaf(v2, w1.z, a21.z); a21.w = fmaf(v2, w1.w, a21.w);
        a30.x = fmaf(v3, w0.x, a30.x); a30.y = fmaf(v3, w0.y, a30.y);
        a30.z = fmaf(v3, w0.z, a30.z); a30.w = fmaf(v3, w0.w, a30.w);
        a31.x = fmaf(v3, w1.x, a31.x); a31.y = fmaf(v3, w1.y, a31.y);
        a31.z = fmaf(v3, w1.z, a31.z); a31.w = fmaf(v3, w1.w, a31.w);
    }
    const float4 A0[4] = {a00, a10, a20, a30};
    const float4 A1[4] = {a01, a11, a21, a31};
    float4* o4 = (float4*)out;
    #pragma unroll
    for (int j = 0; j < 4; j++) {
        const int n = nbase + r0 + 32 * j;
        if (n < N_NODESC) {
            o4[(size_t)n * 16 + g * 2 + 0] = A0[j];
            o4[(size_t)n * 16 + g * 2 + 1] = A1[j];
        }
    }
}

// ---------------------------------------------------------------------------
extern "C" void kernel_launch(void* const* d_in, const int* in_sizes, int n_in,
                              void* d_out, int out_size, void* d_ws, size_t ws_size,
                              hipStream_t stream) {
    const float* x     = (const float*)d_in[0];
    const float* emb   = (const float*)d_in[1];
    const float* eps   = (const float*)d_in[2];
    const float* W1    = (const float*)d_in[3];
    const float* b1    = (const float*)d_in[4];
    const float* gamma = (const float*)d_in[5];
    const float* beta  = (const float*)d_in[6];
    const float* W2    = (const float*)d_in[7];
    const float* b2    = (const float*)d_in[8];
    const int*   ei    = (const int*)d_in[9];
    const int*   ea    = (const int*)d_in[10];
    float* out = (float*)d_out;

    // ws: [cs 64][css 64][gcur NBUCK][tmp NBUCK*BCAPG][xh N*64 bf16]  (~22 MB)
    float* ws    = (float*)d_ws;
    float* cs    = ws;
    float* css   = ws + 64;
    int*   gcur  = (int*)(ws + 128);
    int*   tmp   = gcur + NBUCK;
    ushort* xh   = (ushort*)(tmp + (size_t)NBUCK * BCAPG);

    // zero cs/css/gcur (4.6 KB)
    hipMemsetAsync(d_ws, 0, (size_t)(128 + NBUCK) * sizeof(int), stream);

    k_castsort<<<SBLK, 1024, 0, stream>>>(ei, ea, x, (uint2*)xh, gcur, tmp);
    k_aggmlp1<<<NUSED, 256, 0, stream>>>(xh, emb, x, eps, gcur, tmp,
                                         W1, b1, out, cs, css);   // h1 -> d_out
    k_mlp2<<<NUSED, 256, 0, stream>>>(out, W2, b2, gamma, beta, cs, css, out);
}

// Round 7
// 224.271 us; speedup vs baseline: 5.4736x; 3.4801x over previous
//
#include <hip/hip_runtime.h>

#define N_NODESC 100000
#define N_EDGESC 1600000
#define BN_EPSC 1e-5f
#define NBUCK 1024              // coarse buckets (dst>>7, 128 nodes each), 782 used
#define NUSED 782               // ceil(100000/128)
#define SBLK 256                // castsort blocks
#define EPB (N_EDGESC / SBLK)   // 6250 edges per block
#define NMLP 1563               // ceil(100000/64) — 64-row MLP tiles
#define BCAP 4608               // LDS edge cap per bucket in aggf
#define BCAPG 2304              // global per-bucket stride (mean 1562, ~18 sigma)

// ---------------------------------------------------------------------------
// K_castsort: ONE preprocessing kernel.  (R2 verbatim)
// packed = src(17b) | attr<<17(2b) | (dst&127)<<19(7b).
// ---------------------------------------------------------------------------
__global__ __launch_bounds__(1024) void k_castsort(
    const int* __restrict__ ei, const int* __restrict__ ea,
    const float* __restrict__ x, uint2* __restrict__ xh4,
    int* __restrict__ gcur, int* __restrict__ tmp)
{
    __shared__ int ledge[EPB + 22];     // 6272 sorted packed edges
    __shared__ int cnt[NBUCK];
    __shared__ int cstart[NBUCK + 1];
    __shared__ int cur[NBUCK];
    __shared__ int gofs[NBUCK];
    __shared__ int wtot[16];
    const int t = threadIdx.x;
    const int k = blockIdx.x;

    cnt[t] = 0;
    {   // ---- bf16 cast, batched ----
        const float4* x4 = (const float4*)x;
        const int g = k * 1024 + t;
        float4 v[7];
        bool m[7];
        #pragma unroll
        for (int i = 0; i < 7; i++) {
            const int idx = g + i * (SBLK * 1024);
            m[i] = (idx < N_NODESC * 16);
            if (m[i]) v[i] = x4[idx];
        }
        #pragma unroll
        for (int i = 0; i < 7; i++) {
            if (m[i]) {
                const int idx = g + i * (SBLK * 1024);
                unsigned int a = __float_as_uint(v[i].x);
                unsigned int b = __float_as_uint(v[i].y);
                unsigned int c = __float_as_uint(v[i].z);
                unsigned int d = __float_as_uint(v[i].w);
                a = (a + 0x7FFFu + ((a >> 16) & 1u)) >> 16;
                b = (b + 0x7FFFu + ((b >> 16) & 1u)) >> 16;
                c = (c + 0x7FFFu + ((c >> 16) & 1u)) >> 16;
                d = (d + 0x7FFFu + ((d >> 16) & 1u)) >> 16;
                xh4[idx] = make_uint2(a | (b << 16), c | (d << 16));
            }
        }
    }
    __syncthreads();        // cnt zeroed before counting

    int pk[7], bk[7];
    const int base = k * EPB;
    #pragma unroll
    for (int i = 0; i < 7; i++) {
        const int e = base + i * 1024 + t;
        if (e < base + EPB) {
            const int src = ei[e];
            const int dst = ei[N_EDGESC + e];
            const int a = ea[e];
            pk[i] = src | (a << 17) | ((dst & 127) << 19);
            bk[i] = dst >> 7;
            atomicAdd(&cnt[bk[i]], 1);
        } else bk[i] = -1;
    }
    __syncthreads();

    {   // exclusive scan of 1024 counts
        const int lane = t & 63;
        const int w = t >> 6;
        const int v = cnt[t];
        int inc = v;
        #pragma unroll
        for (int d = 1; d < 64; d <<= 1) {
            const int u = __shfl_up(inc, d);
            if (lane >= d) inc += u;
        }
        if (lane == 63) wtot[w] = inc;
        __syncthreads();
        int add = 0;
        #pragma unroll
        for (int w2 = 0; w2 < 16; w2++) if (w2 < w) add += wtot[w2];
        const int ex = inc - v + add;
        cstart[t] = ex;
        cur[t] = ex;
        if (t == 1023) cstart[NBUCK] = ex + v;
    }
    __syncthreads();

    #pragma unroll
    for (int i = 0; i < 7; i++) {
        if (bk[i] >= 0) {
            const int pos = atomicAdd(&cur[bk[i]], 1);
            ledge[pos] = pk[i];
        }
    }
    {
        const int c = cnt[t];
        if (c > 0) gofs[t] = atomicAdd(&gcur[t], c);
    }
    __syncthreads();

    for (int i = t; i < EPB; i += 1024) {
        int lo = 0, hi = NBUCK;
        #pragma unroll
        for (int s = 0; s < 10; s++) {
            const int mid = (lo + hi) >> 1;
            if (cstart[mid] <= i) lo = mid; else hi = mid;
        }
        const int o = gofs[lo] + (i - cstart[lo]);
        if (o < BCAPG) tmp[lo * BCAPG + o] = ledge[i];
    }
}

// ---------------------------------------------------------------------------
// K_aggf (R2 verbatim — proven 43.4us):
//  512 threads = 64 groups of 8 lanes; group g owns nodes g*2, g*2+1.
//  uint4 xh gathers (16B/lane = 8 bf16); emb staged in LDS.
//  Fusion attempts R3-R6 all hit phase-serialization or regalloc cliffs;
//  standalone gather kernel is the stable optimum for this phase.
// ---------------------------------------------------------------------------
__global__ __launch_bounds__(512) void k_aggf(
    const ushort* __restrict__ xh, const float* __restrict__ emb,
    const float* __restrict__ x, const float* __restrict__ epsp,
    const int* __restrict__ gcur, const int* __restrict__ tmp,
    float* __restrict__ agg)
{
    __shared__ int packedL[BCAP];
    __shared__ int cnt[128];
    __shared__ int cst[128];
    __shared__ int cur[128];
    __shared__ float emL[4][68];        // padded: rows 68 words apart
    const int t = threadIdx.x;
    const int b = blockIdx.x;
    const int start = b * BCAPG;
    int cntb = gcur[b];
    if (cntb > BCAPG) cntb = BCAPG;
    if (t < 128) cnt[t] = 0;
    if (t < 256) emL[t >> 6][t & 63] = emb[t];
    __syncthreads();

    // pass 1: per-node counts
    for (int e = t; e < cntb; e += 512)
        atomicAdd(&cnt[(tmp[start + e] >> 19) & 127], 1);
    __syncthreads();
    if (t < 64) {   // scan 128 counts (two 64-lane halves)
        const int lane = t;
        const int v0 = cnt[lane];
        const int v1 = cnt[64 + lane];
        int i0 = v0, i1 = v1;
        #pragma unroll
        for (int d = 1; d < 64; d <<= 1) {
            const int u0 = __shfl_up(i0, d);
            const int u1 = __shfl_up(i1, d);
            if (lane >= d) { i0 += u0; i1 += u1; }
        }
        const int tot0 = __shfl(i0, 63);
        cst[lane] = i0 - v0;
        cst[64 + lane] = tot0 + i1 - v1;
        cur[lane] = i0 - v0;
        cur[64 + lane] = tot0 + i1 - v1;
    }
    __syncthreads();
    // pass 2: place node-sorted into LDS
    for (int e = t; e < cntb; e += 512) {
        const int p = tmp[start + e];
        const int pos = atomicAdd(&cur[(p >> 19) & 127], 1);
        if (pos < BCAP) packedL[pos] = p;
    }
    __syncthreads();

    // aggregate: group g -> nodes g*2, g*2+1; lane q = feature octet
    const int g = t >> 3;
    const int q = t & 7;                 // floats [q*8, q*8+8)
    const float sc1 = 1.0f + epsp[0];
    const uint4* xv8 = (const uint4*)xh; // 16B = 8 bf16 per lane
    const float4* x4 = (const float4*)x;
    float4* o4 = (float4*)agg;
    const float* eq = &emL[0][0] + q * 8;
    for (int j = 0; j < 2; j++) {
        const int nl = g * 2 + j;
        const int n = b * 128 + nl;
        int e = cst[nl];
        const int ee = cur[nl];           // cur == end after pass 2
        float4 aL = make_float4(0.f, 0.f, 0.f, 0.f);
        float4 aH = make_float4(0.f, 0.f, 0.f, 0.f);
        if (n < N_NODESC) {
            const float4 v0 = x4[(size_t)n * 16 + q * 2];
            const float4 v1 = x4[(size_t)n * 16 + q * 2 + 1];
            aL.x = sc1 * v0.x; aL.y = sc1 * v0.y;
            aL.z = sc1 * v0.z; aL.w = sc1 * v0.w;
            aH.x = sc1 * v1.x; aH.y = sc1 * v1.y;
            aH.z = sc1 * v1.z; aH.w = sc1 * v1.w;
        }
        for (; e + 2 <= ee; e += 2) {
            const int p0 = packedL[e];
            const int p1 = packedL[e + 1];
            const uint4 u0 = xv8[(size_t)(p0 & 0x1FFFF) * 8 + q];
            const uint4 u1 = xv8[(size_t)(p1 & 0x1FFFF) * 8 + q];
            const float* e0 = eq + ((p0 >> 17) & 3) * 68;
            const float* e1 = eq + ((p1 >> 17) & 3) * 68;
            const float4 t0L = *(const float4*)(e0);
            const float4 t0H = *(const float4*)(e0 + 4);
            const float4 t1L = *(const float4*)(e1);
            const float4 t1H = *(const float4*)(e1 + 4);
            aL.x += fmaxf(__uint_as_float(u0.x << 16)          + t0L.x, 0.f)
                  + fmaxf(__uint_as_float(u1.x << 16)          + t1L.x, 0.f);
            aL.y += fmaxf(__uint_as_float(u0.x & 0xFFFF0000u)  + t0L.y, 0.f)
                  + fmaxf(__uint_as_float(u1.x & 0xFFFF0000u)  + t1L.y, 0.f);
            aL.z += fmaxf(__uint_as_float(u0.y << 16)          + t0L.z, 0.f)
                  + fmaxf(__uint_as_float(u1.y << 16)          + t1L.z, 0.f);
            aL.w += fmaxf(__uint_as_float(u0.y & 0xFFFF0000u)  + t0L.w, 0.f)
                  + fmaxf(__uint_as_float(u1.y & 0xFFFF0000u)  + t1L.w, 0.f);
            aH.x += fmaxf(__uint_as_float(u0.z << 16)          + t0H.x, 0.f)
                  + fmaxf(__uint_as_float(u1.z << 16)          + t1H.x, 0.f);
            aH.y += fmaxf(__uint_as_float(u0.z & 0xFFFF0000u)  + t0H.y, 0.f)
                  + fmaxf(__uint_as_float(u1.z & 0xFFFF0000u)  + t1H.y, 0.f);
            aH.z += fmaxf(__uint_as_float(u0.w << 16)          + t0H.z, 0.f)
                  + fmaxf(__uint_as_float(u1.w << 16)          + t1H.z, 0.f);
            aH.w += fmaxf(__uint_as_float(u0.w & 0xFFFF0000u)  + t0H.w, 0.f)
                  + fmaxf(__uint_as_float(u1.w & 0xFFFF0000u)  + t1H.w, 0.f);
        }
        for (; e < ee; e++) {
            const int p0 = packedL[e];
            const uint4 u0 = xv8[(size_t)(p0 & 0x1FFFF) * 8 + q];
            const float* e0 = eq + ((p0 >> 17) & 3) * 68;
            const float4 t0L = *(const float4*)(e0);
            const float4 t0H = *(const float4*)(e0 + 4);
            aL.x += fmaxf(__uint_as_float(u0.x << 16)         + t0L.x, 0.f);
            aL.y += fmaxf(__uint_as_float(u0.x & 0xFFFF0000u) + t0L.y, 0.f);
            aL.z += fmaxf(__uint_as_float(u0.y << 16)         + t0L.z, 0.f);
            aL.w += fmaxf(__uint_as_float(u0.y & 0xFFFF0000u) + t0L.w, 0.f);
            aH.x += fmaxf(__uint_as_float(u0.z << 16)         + t0H.x, 0.f);
            aH.y += fmaxf(__uint_as_float(u0.z & 0xFFFF0000u) + t0H.y, 0.f);
            aH.z += fmaxf(__uint_as_float(u0.w << 16)         + t0H.z, 0.f);
            aH.w += fmaxf(__uint_as_float(u0.w & 0xFFFF0000u) + t0H.w, 0.f);
        }
        if (n < N_NODESC) {
            o4[(size_t)n * 16 + q * 2]     = aL;
            o4[(size_t)n * 16 + q * 2 + 1] = aH;
        }
    }
}

// ---------------------------------------------------------------------------
// K_mlp1 (64-row tiles): hbuf := hbuf @ W1 + b1 ; BN column sums.
//  R2's 128-row version ran 43.9us at occ 14.4% (53KB LDS -> 3 blk/CU,
//  load->barrier->GEMM convoy).  64-row tile: LDS 35.8KB -> 4 blk/CU
//  (16 waves/CU), grid 1563, half the exposed pre-barrier load.
//  2 rows x 8 cols per thread.
// ---------------------------------------------------------------------------
__global__ __launch_bounds__(256) void k_mlp1(
    float* hbuf,
    const float* __restrict__ W1, const float* __restrict__ b1,
    float* __restrict__ cs, float* __restrict__ css)
{
    __shared__ float lin[64][68];
    __shared__ float lW[4096];
    __shared__ float redS[4][64];
    __shared__ float redQ[4][64];
    const int t = threadIdx.x;
    const int nbase = blockIdx.x * 64;

    {
        const float4* W4 = (const float4*)W1;
        float4* lW4 = (float4*)lW;
        #pragma unroll
        for (int i = 0; i < 4; i++) lW4[i * 256 + t] = W4[i * 256 + t];
    }
    {
        const float4* a4 = (const float4*)hbuf;
        #pragma unroll
        for (int i = 0; i < 4; i++) {
            const int fidx = i * 256 + t;
            const int row = fidx >> 4;
            const int q = fidx & 15;
            const int n = nbase + row;
            float4 v = make_float4(0.f, 0.f, 0.f, 0.f);
            if (n < N_NODESC) v = a4[(size_t)n * 16 + q];
            *(float4*)&lin[row][q * 4] = v;
        }
    }
    __syncthreads();

    const int g = t & 7;           // col group: cols [g*8, g*8+8)
    const int r0 = t >> 3;         // rows r0, r0+32
    const float4* lW4 = (const float4*)lW;
    const float4* b4 = (const float4*)b1;
    const float4 bb0 = b4[g * 2 + 0];
    const float4 bb1 = b4[g * 2 + 1];
    float4 a00 = bb0, a01 = bb1;   // row r0
    float4 a10 = bb0, a11 = bb1;   // row r0+32
    for (int k = 0; k < 64; k++) {
        const float v0 = lin[r0][k];
        const float v1 = lin[r0 + 32][k];
        const float4 w0 = lW4[k * 16 + g * 2 + 0];
        const float4 w1 = lW4[k * 16 + g * 2 + 1];
        a00.x = fmaf(v0, w0.x, a00.x); a00.y = fmaf(v0, w0.y, a00.y);
        a00.z = fmaf(v0, w0.z, a00.z); a00.w = fmaf(v0, w0.w, a00.w);
        a01.x = fmaf(v0, w1.x, a01.x); a01.y = fmaf(v0, w1.y, a01.y);
        a01.z = fmaf(v0, w1.z, a01.z); a01.w = fmaf(v0, w1.w, a01.w);
        a10.x = fmaf(v1, w0.x, a10.x); a10.y = fmaf(v1, w0.y, a10.y);
        a10.z = fmaf(v1, w0.z, a10.z); a10.w = fmaf(v1, w0.w, a10.w);
        a11.x = fmaf(v1, w1.x, a11.x); a11.y = fmaf(v1, w1.y, a11.y);
        a11.z = fmaf(v1, w1.z, a11.z); a11.w = fmaf(v1, w1.w, a11.w);
    }

    const float4 A0[2] = {a00, a10};
    const float4 A1[2] = {a01, a11};
    float4* h4 = (float4*)hbuf;
    float vs[8], vq[8];
    #pragma unroll
    for (int c = 0; c < 8; c++) { vs[c] = 0.f; vq[c] = 0.f; }
    #pragma unroll
    for (int m = 0; m < 2; m++) {
        const int n = nbase + r0 + 32 * m;
        const float mk = (n < N_NODESC) ? 1.0f : 0.0f;
        if (n < N_NODESC) {
            h4[(size_t)n * 16 + g * 2 + 0] = A0[m];
            h4[(size_t)n * 16 + g * 2 + 1] = A1[m];
        }
        const float e0[8] = {A0[m].x, A0[m].y, A0[m].z, A0[m].w,
                             A1[m].x, A1[m].y, A1[m].z, A1[m].w};
        #pragma unroll
        for (int c = 0; c < 8; c++) {
            const float v = e0[c] * mk;
            vs[c] += v;
            vq[c] += v * e0[c];
        }
    }
    #pragma unroll
    for (int o = 8; o < 64; o <<= 1) {
        #pragma unroll
        for (int c = 0; c < 8; c++) {
            vs[c] += __shfl_xor(vs[c], o);
            vq[c] += __shfl_xor(vq[c], o);
        }
    }
    const int lane = t & 63;
    const int w = t >> 6;
    if (lane < 8) {
        #pragma unroll
        for (int c = 0; c < 8; c++) {
            redS[w][lane * 8 + c] = vs[c];
            redQ[w][lane * 8 + c] = vq[c];
        }
    }
    __syncthreads();
    if (t < 64) {
        const float s = redS[0][t] + redS[1][t] + redS[2][t] + redS[3][t];
        const float qq = redQ[0][t] + redQ[1][t] + redQ[2][t] + redQ[3][t];
        unsafeAtomicAdd(&cs[t], s);
        unsafeAtomicAdd(&css[t], qq);
    }
}

// ---------------------------------------------------------------------------
// K_mlp2 (64-row tiles): out = relu(BN(h1)) @ W2 + b2.  h1 aliases out.
// ---------------------------------------------------------------------------
__global__ __launch_bounds__(256) void k_mlp2(
    const float* h1, const float* __restrict__ W2, const float* __restrict__ b2,
    const float* __restrict__ gamma, const float* __restrict__ beta,
    const float* __restrict__ cs, const float* __restrict__ css,
    float* out)
{
    __shared__ float lin[64][68];
    __shared__ float lW[4096];
    __shared__ float scl[64];
    __shared__ float sft[64];
    const int t = threadIdx.x;
    const int nbase = blockIdx.x * 64;

    if (t < 64) {
        const float inv = 1.0f / (float)N_NODESC;
        const float mu = cs[t] * inv;
        const float var = css[t] * inv - mu * mu;
        const float rs = rsqrtf(var + BN_EPSC);
        const float s = rs * gamma[t];
        scl[t] = s;
        sft[t] = fmaf(-mu, s, beta[t]);
    }
    {
        const float4* W4 = (const float4*)W2;
        float4* lW4 = (float4*)lW;
        #pragma unroll
        for (int i = 0; i < 4; i++) lW4[i * 256 + t] = W4[i * 256 + t];
    }
    __syncthreads();
    {
        const float4* h4 = (const float4*)h1;
        #pragma unroll
        for (int i = 0; i < 4; i++) {
            const int fidx = i * 256 + t;
            const int row = fidx >> 4;
            const int q = fidx & 15;
            const int n = nbase + row;
            float4 v = make_float4(0.f, 0.f, 0.f, 0.f);
            if (n < N_NODESC) {
                const float4 h = h4[(size_t)n * 16 + q];
                const int c = q * 4;
                v.x = fmaxf(fmaf(h.x, scl[c + 0], sft[c + 0]), 0.f);
                v.y = fmaxf(fmaf(h.y, scl[c + 1], sft[c + 1]), 0.f);
                v.z = fmaxf(fmaf(h.z, scl[c + 2], sft[c + 2]), 0.f);
                v.w = fmaxf(fmaf(h.w, scl[c + 3], sft[c + 3]), 0.f);
            }
            *(float4*)&lin[row][q * 4] = v;
        }
    }
    __syncthreads();

    const int g = t & 7;
    const int r0 = t >> 3;
    const float4* lW4 = (const float4*)lW;
    const float4* b4 = (const float4*)b2;
    const float4 bb0 = b4[g * 2 + 0];
    const float4 bb1 = b4[g * 2 + 1];
    float4 a00 = bb0, a01 = bb1;
    float4 a10 = bb0, a11 = bb1;
    for (int k = 0; k < 64; k++) {
        const float v0 = lin[r0][k];
        const float v1 = lin[r0 + 32][k];
        const float4 w0 = lW4[k * 16 + g * 2 + 0];
        const float4 w1 = lW4[k * 16 + g * 2 + 1];
        a00.x = fmaf(v0, w0.x, a00.x); a00.y = fmaf(v0, w0.y, a00.y);
        a00.z = fmaf(v0, w0.z, a00.z); a00.w = fmaf(v0, w0.w, a00.w);
        a01.x = fmaf(v0, w1.x, a01.x); a01.y = fmaf(v0, w1.y, a01.y);
        a01.z = fmaf(v0, w1.z, a01.z); a01.w = fmaf(v0, w1.w, a01.w);
        a10.x = fmaf(v1, w0.x, a10.x); a10.y = fmaf(v1, w0.y, a10.y);
        a10.z = fmaf(v1, w0.z, a10.z); a10.w = fmaf(v1, w0.w, a10.w);
        a11.x = fmaf(v1, w1.x, a11.x); a11.y = fmaf(v1, w1.y, a11.y);
        a11.z = fmaf(v1, w1.z, a11.z); a11.w = fmaf(v1, w1.w, a11.w);
    }
    const float4 A0[2] = {a00, a10};
    const float4 A1[2] = {a01, a11};
    float4* o4 = (float4*)out;
    #pragma unroll
    for (int m = 0; m < 2; m++) {
        const int n = nbase + r0 + 32 * m;
        if (n < N_NODESC) {
            o4[(size_t)n * 16 + g * 2 + 0] = A0[m];
            o4[(size_t)n * 16 + g * 2 + 1] = A1[m];
        }
    }
}

// ---------------------------------------------------------------------------
extern "C" void kernel_launch(void* const* d_in, const int* in_sizes, int n_in,
                              void* d_out, int out_size, void* d_ws, size_t ws_size,
                              hipStream_t stream) {
    const float* x     = (const float*)d_in[0];
    const float* emb   = (const float*)d_in[1];
    const float* eps   = (const float*)d_in[2];
    const float* W1    = (const float*)d_in[3];
    const float* b1    = (const float*)d_in[4];
    const float* gamma = (const float*)d_in[5];
    const float* beta  = (const float*)d_in[6];
    const float* W2    = (const float*)d_in[7];
    const float* b2    = (const float*)d_in[8];
    const int*   ei    = (const int*)d_in[9];
    const int*   ea    = (const int*)d_in[10];
    float* out = (float*)d_out;

    // ws: [cs 64][css 64][gcur NBUCK][tmp NBUCK*BCAPG][xh N*64 bf16]  (~22 MB)
    float* ws    = (float*)d_ws;
    float* cs    = ws;
    float* css   = ws + 64;
    int*   gcur  = (int*)(ws + 128);
    int*   tmp   = gcur + NBUCK;
    ushort* xh   = (ushort*)(tmp + (size_t)NBUCK * BCAPG);

    // zero cs/css/gcur (4.6 KB)
    hipMemsetAsync(d_ws, 0, (size_t)(128 + NBUCK) * sizeof(int), stream);

    k_castsort<<<SBLK, 1024, 0, stream>>>(ei, ea, x, (uint2*)xh, gcur, tmp);
    k_aggf<<<NUSED, 512, 0, stream>>>(xh, emb, x, eps, gcur, tmp, out);   // (1+eps)x+agg -> d_out
    k_mlp1<<<NMLP, 256, 0, stream>>>(out, W1, b1, cs, css);               // h1 -> d_out
    k_mlp2<<<NMLP, 256, 0, stream>>>(out, W2, b2, gamma, beta, cs, css, out);
}

// Round 8
// 204.779 us; speedup vs baseline: 5.9946x; 1.0952x over previous
//
#include <hip/hip_runtime.h>

#define N_NODESC 100000
#define N_EDGESC 1600000
#define BN_EPSC 1e-5f
#define NBUCK 1024              // coarse buckets (dst>>7, 128 nodes each), 782 used
#define NUSED 782               // ceil(100000/128)
#define SBLK 256                // castsort blocks
#define EPB (N_EDGESC / SBLK)   // 6250 edges per block
#define MT 128                  // nodes per MLP block
#define BCAPG 2304              // global per-bucket stride (mean 1562, ~18 sigma)

// ---------------------------------------------------------------------------
// K_castsort: ONE preprocessing kernel.  (R2 verbatim — proven)
// packed = src(17b) | attr<<17(2b) | (dst&127)<<19(7b).
// ---------------------------------------------------------------------------
__global__ __launch_bounds__(1024) void k_castsort(
    const int* __restrict__ ei, const int* __restrict__ ea,
    const float* __restrict__ x, uint2* __restrict__ xh4,
    int* __restrict__ gcur, int* __restrict__ tmp)
{
    __shared__ int ledge[EPB + 22];     // 6272 sorted packed edges
    __shared__ int cnt[NBUCK];
    __shared__ int cstart[NBUCK + 1];
    __shared__ int cur[NBUCK];
    __shared__ int gofs[NBUCK];
    __shared__ int wtot[16];
    const int t = threadIdx.x;
    const int k = blockIdx.x;

    cnt[t] = 0;
    {   // ---- bf16 cast, batched ----
        const float4* x4 = (const float4*)x;
        const int g = k * 1024 + t;
        float4 v[7];
        bool m[7];
        #pragma unroll
        for (int i = 0; i < 7; i++) {
            const int idx = g + i * (SBLK * 1024);
            m[i] = (idx < N_NODESC * 16);
            if (m[i]) v[i] = x4[idx];
        }
        #pragma unroll
        for (int i = 0; i < 7; i++) {
            if (m[i]) {
                const int idx = g + i * (SBLK * 1024);
                unsigned int a = __float_as_uint(v[i].x);
                unsigned int b = __float_as_uint(v[i].y);
                unsigned int c = __float_as_uint(v[i].z);
                unsigned int d = __float_as_uint(v[i].w);
                a = (a + 0x7FFFu + ((a >> 16) & 1u)) >> 16;
                b = (b + 0x7FFFu + ((b >> 16) & 1u)) >> 16;
                c = (c + 0x7FFFu + ((c >> 16) & 1u)) >> 16;
                d = (d + 0x7FFFu + ((d >> 16) & 1u)) >> 16;
                xh4[idx] = make_uint2(a | (b << 16), c | (d << 16));
            }
        }
    }
    __syncthreads();        // cnt zeroed before counting

    int pk[7], bk[7];
    const int base = k * EPB;
    #pragma unroll
    for (int i = 0; i < 7; i++) {
        const int e = base + i * 1024 + t;
        if (e < base + EPB) {
            const int src = ei[e];
            const int dst = ei[N_EDGESC + e];
            const int a = ea[e];
            pk[i] = src | (a << 17) | ((dst & 127) << 19);
            bk[i] = dst >> 7;
            atomicAdd(&cnt[bk[i]], 1);
        } else bk[i] = -1;
    }
    __syncthreads();

    {   // exclusive scan of 1024 counts
        const int lane = t & 63;
        const int w = t >> 6;
        const int v = cnt[t];
        int inc = v;
        #pragma unroll
        for (int d = 1; d < 64; d <<= 1) {
            const int u = __shfl_up(inc, d);
            if (lane >= d) inc += u;
        }
        if (lane == 63) wtot[w] = inc;
        __syncthreads();
        int add = 0;
        #pragma unroll
        for (int w2 = 0; w2 < 16; w2++) if (w2 < w) add += wtot[w2];
        const int ex = inc - v + add;
        cstart[t] = ex;
        cur[t] = ex;
        if (t == 1023) cstart[NBUCK] = ex + v;
    }
    __syncthreads();

    #pragma unroll
    for (int i = 0; i < 7; i++) {
        if (bk[i] >= 0) {
            const int pos = atomicAdd(&cur[bk[i]], 1);
            ledge[pos] = pk[i];
        }
    }
    {
        const int c = cnt[t];
        if (c > 0) gofs[t] = atomicAdd(&gcur[t], c);
    }
    __syncthreads();

    for (int i = t; i < EPB; i += 1024) {
        int lo = 0, hi = NBUCK;
        #pragma unroll
        for (int s = 0; s < 10; s++) {
            const int mid = (lo + hi) >> 1;
            if (cstart[mid] <= i) lo = mid; else hi = mid;
        }
        const int o = gofs[lo] + (i - cstart[lo]);
        if (o < BCAPG) tmp[lo * BCAPG + o] = ledge[i];
    }
}

// ---------------------------------------------------------------------------
// K_aggmlp1 (R3 structure — measured best at 202.7us total):
//  phase A: per-bucket node-sort + register gather -> LDS lin[][]
//  ONE barrier; phase B: h1 = lin @ W1 + b1 (4 rows x 8 cols/thread),
//  store h1, BN sums.
//  R7-round tweaks (structure-preserving only, after R4/R5/R6 regalloc
//  disasters): (a) packedL sized to its true bound BCAPG (pos < cntb <=
//  BCAPG always) — LDS 72704 -> 63488; (b) GEMM k-loop unrolled x2 so
//  adjacent lin[r][k],lin[r][k+1] fuse into ds_read_b64 — LDS instrs
//  per 2-k drop 12 -> 8 in the LDS-pipe-bound GEMM phase.
// ---------------------------------------------------------------------------
__global__ __launch_bounds__(512) void k_aggmlp1(
    const ushort* __restrict__ xh, const float* __restrict__ emb,
    const float* __restrict__ x, const float* __restrict__ epsp,
    const int* __restrict__ gcur, const int* __restrict__ tmp,
    const float* __restrict__ W1, const float* __restrict__ b1,
    float* __restrict__ out, float* __restrict__ cs, float* __restrict__ css)
{
    __shared__ int packedL[BCAPG];      // 9216B; aliased by redS/redQ at end
    __shared__ float lin[MT][68];       // 34816B
    __shared__ float lW[4096];          // 16384B
    __shared__ int cnt[128];
    __shared__ int cst[128];
    __shared__ int cur[128];
    __shared__ float emL[4][68];        // padded: rows 68 words apart
    const int t = threadIdx.x;
    const int b = blockIdx.x;
    const int start = b * BCAPG;

    {   // ---- stage W1 early: latency hides under the whole sort phase ---
        const float4* W4 = (const float4*)W1;
        float4* lW4s = (float4*)lW;
        lW4s[t] = W4[t];
        lW4s[512 + t] = W4[512 + t];
    }
    int cntb = gcur[b];
    if (cntb > BCAPG) cntb = BCAPG;
    if (t < 128) cnt[t] = 0;
    if (t < 256) emL[t >> 6][t & 63] = emb[t];
    __syncthreads();

    // pass 1: per-node counts
    for (int e = t; e < cntb; e += 512)
        atomicAdd(&cnt[(tmp[start + e] >> 19) & 127], 1);
    __syncthreads();
    if (t < 64) {   // scan 128 counts (two 64-lane halves)
        const int lane = t;
        const int v0 = cnt[lane];
        const int v1 = cnt[64 + lane];
        int i0 = v0, i1 = v1;
        #pragma unroll
        for (int d = 1; d < 64; d <<= 1) {
            const int u0 = __shfl_up(i0, d);
            const int u1 = __shfl_up(i1, d);
            if (lane >= d) { i0 += u0; i1 += u1; }
        }
        const int tot0 = __shfl(i0, 63);
        cst[lane] = i0 - v0;
        cst[64 + lane] = tot0 + i1 - v1;
        cur[lane] = i0 - v0;
        cur[64 + lane] = tot0 + i1 - v1;
    }
    __syncthreads();
    // pass 2: place node-sorted into LDS
    for (int e = t; e < cntb; e += 512) {
        const int p = tmp[start + e];
        const int pos = atomicAdd(&cur[(p >> 19) & 127], 1);
        if (pos < BCAPG) packedL[pos] = p;
    }
    __syncthreads();

    // ---- phase A: aggregate; group g -> nodes g*2,g*2+1; lane q = octet -
    {
        const int g = t >> 3;
        const int q = t & 7;                 // floats [q*8, q*8+8)
        const float sc1 = 1.0f + epsp[0];
        const uint4* xv8 = (const uint4*)xh; // 16B = 8 bf16 per lane
        const float4* x4 = (const float4*)x;
        const float* eq = &emL[0][0] + q * 8;
        for (int j = 0; j < 2; j++) {
            const int nl = g * 2 + j;
            const int n = b * 128 + nl;
            int e = cst[nl];
            const int ee = cur[nl];           // cur == end after pass 2
            float4 aL = make_float4(0.f, 0.f, 0.f, 0.f);
            float4 aH = make_float4(0.f, 0.f, 0.f, 0.f);
            if (n < N_NODESC) {
                const float4 v0 = x4[(size_t)n * 16 + q * 2];
                const float4 v1 = x4[(size_t)n * 16 + q * 2 + 1];
                aL.x = sc1 * v0.x; aL.y = sc1 * v0.y;
                aL.z = sc1 * v0.z; aL.w = sc1 * v0.w;
                aH.x = sc1 * v1.x; aH.y = sc1 * v1.y;
                aH.z = sc1 * v1.z; aH.w = sc1 * v1.w;
            }
            for (; e + 2 <= ee; e += 2) {
                const int p0 = packedL[e];
                const int p1 = packedL[e + 1];
                const uint4 u0 = xv8[(size_t)(p0 & 0x1FFFF) * 8 + q];
                const uint4 u1 = xv8[(size_t)(p1 & 0x1FFFF) * 8 + q];
                const float* e0 = eq + ((p0 >> 17) & 3) * 68;
                const float* e1 = eq + ((p1 >> 17) & 3) * 68;
                const float4 t0L = *(const float4*)(e0);
                const float4 t0H = *(const float4*)(e0 + 4);
                const float4 t1L = *(const float4*)(e1);
                const float4 t1H = *(const float4*)(e1 + 4);
                aL.x += fmaxf(__uint_as_float(u0.x << 16)          + t0L.x, 0.f)
                      + fmaxf(__uint_as_float(u1.x << 16)          + t1L.x, 0.f);
                aL.y += fmaxf(__uint_as_float(u0.x & 0xFFFF0000u)  + t0L.y, 0.f)
                      + fmaxf(__uint_as_float(u1.x & 0xFFFF0000u)  + t1L.y, 0.f);
                aL.z += fmaxf(__uint_as_float(u0.y << 16)          + t0L.z, 0.f)
                      + fmaxf(__uint_as_float(u1.y << 16)          + t1L.z, 0.f);
                aL.w += fmaxf(__uint_as_float(u0.y & 0xFFFF0000u)  + t0L.w, 0.f)
                      + fmaxf(__uint_as_float(u1.y & 0xFFFF0000u)  + t1L.w, 0.f);
                aH.x += fmaxf(__uint_as_float(u0.z << 16)          + t0H.x, 0.f)
                      + fmaxf(__uint_as_float(u1.z << 16)          + t1H.x, 0.f);
                aH.y += fmaxf(__uint_as_float(u0.z & 0xFFFF0000u)  + t0H.y, 0.f)
                      + fmaxf(__uint_as_float(u1.z & 0xFFFF0000u)  + t1H.y, 0.f);
                aH.z += fmaxf(__uint_as_float(u0.w << 16)          + t0H.z, 0.f)
                      + fmaxf(__uint_as_float(u1.w << 16)          + t1H.z, 0.f);
                aH.w += fmaxf(__uint_as_float(u0.w & 0xFFFF0000u)  + t0H.w, 0.f)
                      + fmaxf(__uint_as_float(u1.w & 0xFFFF0000u)  + t1H.w, 0.f);
            }
            for (; e < ee; e++) {
                const int p0 = packedL[e];
                const uint4 u0 = xv8[(size_t)(p0 & 0x1FFFF) * 8 + q];
                const float* e0 = eq + ((p0 >> 17) & 3) * 68;
                const float4 t0L = *(const float4*)(e0);
                const float4 t0H = *(const float4*)(e0 + 4);
                aL.x += fmaxf(__uint_as_float(u0.x << 16)         + t0L.x, 0.f);
                aL.y += fmaxf(__uint_as_float(u0.x & 0xFFFF0000u) + t0L.y, 0.f);
                aL.z += fmaxf(__uint_as_float(u0.y << 16)         + t0L.z, 0.f);
                aL.w += fmaxf(__uint_as_float(u0.y & 0xFFFF0000u) + t0L.w, 0.f);
                aH.x += fmaxf(__uint_as_float(u0.z << 16)         + t0H.x, 0.f);
                aH.y += fmaxf(__uint_as_float(u0.z & 0xFFFF0000u) + t0H.y, 0.f);
                aH.z += fmaxf(__uint_as_float(u0.w << 16)         + t0H.z, 0.f);
                aH.w += fmaxf(__uint_as_float(u0.w & 0xFFFF0000u) + t0H.w, 0.f);
            }
            // h_pre -> LDS tile (own cells only; no cross-thread hazard)
            *(float4*)&lin[nl][q * 8]     = aL;
            *(float4*)&lin[nl][q * 8 + 4] = aH;
        }
    }
    __syncthreads();    // lin complete + lW visible

    // ---- phase B: h1 = lin @ W1 + b1 ; store; BN sums -------------------
    // k unrolled x2: lin[r][k],lin[r][k+1] adjacent -> ds_read_b64 fusion.
    const int gc = t & 7;          // col group: cols [gc*8, gc*8+8)
    const int r0 = t >> 3;         // rows r0, r0+64
    const float4* lW4 = (const float4*)lW;
    const float4* b4 = (const float4*)b1;
    const float4 bb0 = b4[gc * 2 + 0];
    const float4 bb1 = b4[gc * 2 + 1];
    float4 a00 = bb0, a01 = bb1;   // row r0
    float4 a10 = bb0, a11 = bb1;   // row r0+64
    for (int k = 0; k < 64; k += 2) {
        const float v0a = lin[r0][k];
        const float v0b = lin[r0][k + 1];
        const float v1a = lin[r0 + 64][k];
        const float v1b = lin[r0 + 64][k + 1];
        const float4 w0a = lW4[k * 16 + gc * 2 + 0];
        const float4 w1a = lW4[k * 16 + gc * 2 + 1];
        const float4 w0b = lW4[(k + 1) * 16 + gc * 2 + 0];
        const float4 w1b = lW4[(k + 1) * 16 + gc * 2 + 1];
        a00.x = fmaf(v0a, w0a.x, a00.x); a00.y = fmaf(v0a, w0a.y, a00.y);
        a00.z = fmaf(v0a, w0a.z, a00.z); a00.w = fmaf(v0a, w0a.w, a00.w);
        a01.x = fmaf(v0a, w1a.x, a01.x); a01.y = fmaf(v0a, w1a.y, a01.y);
        a01.z = fmaf(v0a, w1a.z, a01.z); a01.w = fmaf(v0a, w1a.w, a01.w);
        a10.x = fmaf(v1a, w0a.x, a10.x); a10.y = fmaf(v1a, w0a.y, a10.y);
        a10.z = fmaf(v1a, w0a.z, a10.z); a10.w = fmaf(v1a, w0a.w, a10.w);
        a11.x = fmaf(v1a, w1a.x, a11.x); a11.y = fmaf(v1a, w1a.y, a11.y);
        a11.z = fmaf(v1a, w1a.z, a11.z); a11.w = fmaf(v1a, w1a.w, a11.w);
        a00.x = fmaf(v0b, w0b.x, a00.x); a00.y = fmaf(v0b, w0b.y, a00.y);
        a00.z = fmaf(v0b, w0b.z, a00.z); a00.w = fmaf(v0b, w0b.w, a00.w);
        a01.x = fmaf(v0b, w1b.x, a01.x); a01.y = fmaf(v0b, w1b.y, a01.y);
        a01.z = fmaf(v0b, w1b.z, a01.z); a01.w = fmaf(v0b, w1b.w, a01.w);
        a10.x = fmaf(v1b, w0b.x, a10.x); a10.y = fmaf(v1b, w0b.y, a10.y);
        a10.z = fmaf(v1b, w0b.z, a10.z); a10.w = fmaf(v1b, w0b.w, a10.w);
        a11.x = fmaf(v1b, w1b.x, a11.x); a11.y = fmaf(v1b, w1b.y, a11.y);
        a11.z = fmaf(v1b, w1b.z, a11.z); a11.w = fmaf(v1b, w1b.w, a11.w);
    }
    const int n0 = b * MT + r0;
    const int n1 = n0 + 64;
    const float msk0 = (n0 < N_NODESC) ? 1.0f : 0.0f;
    const float msk1 = (n1 < N_NODESC) ? 1.0f : 0.0f;
    float4* o4 = (float4*)out;
    if (n0 < N_NODESC) {
        o4[(size_t)n0 * 16 + gc * 2 + 0] = a00;
        o4[(size_t)n0 * 16 + gc * 2 + 1] = a01;
    }
    if (n1 < N_NODESC) {
        o4[(size_t)n1 * 16 + gc * 2 + 0] = a10;
        o4[(size_t)n1 * 16 + gc * 2 + 1] = a11;
    }

    float vs[8], vq[8];
    {
        const float e0[8] = {a00.x, a00.y, a00.z, a00.w,
                             a01.x, a01.y, a01.z, a01.w};
        const float e1[8] = {a10.x, a10.y, a10.z, a10.w,
                             a11.x, a11.y, a11.z, a11.w};
        #pragma unroll
        for (int c = 0; c < 8; c++) {
            const float v0 = e0[c] * msk0;
            const float v1 = e1[c] * msk1;
            vs[c] = v0 + v1;
            vq[c] = v0 * e0[c] + v1 * e1[c];
        }
    }
    #pragma unroll
    for (int o = 8; o < 64; o <<= 1) {
        #pragma unroll
        for (int c = 0; c < 8; c++) {
            vs[c] += __shfl_xor(vs[c], o);
            vq[c] += __shfl_xor(vq[c], o);
        }
    }
    __syncthreads();    // all lin reads done before redS/redQ alias packedL
    float* redS = (float*)packedL;          // [8][64]
    float* redQ = redS + 512;
    const int lane = t & 63;
    const int w = t >> 6;
    if (lane < 8) {     // lane==gc for these lanes
        #pragma unroll
        for (int c = 0; c < 8; c++) {
            redS[w * 64 + lane * 8 + c] = vs[c];
            redQ[w * 64 + lane * 8 + c] = vq[c];
        }
    }
    __syncthreads();
    if (t < 64) {
        float s = 0.f, qq = 0.f;
        #pragma unroll
        for (int w2 = 0; w2 < 8; w2++) {
            s  += redS[w2 * 64 + t];
            qq += redQ[w2 * 64 + t];
        }
        unsafeAtomicAdd(&cs[t], s);
        unsafeAtomicAdd(&css[t], qq);
    }
}

// ---------------------------------------------------------------------------
// K_mlp2 (R2 128-row verbatim): out = relu(BN(h1)) @ W2 + b2.
// ---------------------------------------------------------------------------
__global__ __launch_bounds__(256) void k_mlp2(
    const float* h1, const float* __restrict__ W2, const float* __restrict__ b2,
    const float* __restrict__ gamma, const float* __restrict__ beta,
    const float* __restrict__ cs, const float* __restrict__ css,
    float* out)
{
    __shared__ float lin[MT][68];
    __shared__ float lW[4096];
    __shared__ float scl[64];
    __shared__ float sft[64];
    const int t = threadIdx.x;
    const int nbase = blockIdx.x * MT;

    if (t < 64) {
        const float inv = 1.0f / (float)N_NODESC;
        const float mu = cs[t] * inv;
        const float var = css[t] * inv - mu * mu;
        const float rs = rsqrtf(var + BN_EPSC);
        const float s = rs * gamma[t];
        scl[t] = s;
        sft[t] = fmaf(-mu, s, beta[t]);
    }
    {
        const float4* W4 = (const float4*)W2;
        float4* lW4 = (float4*)lW;
        #pragma unroll
        for (int i = 0; i < 4; i++) lW4[i * 256 + t] = W4[i * 256 + t];
    }
    __syncthreads();
    {
        const float4* h4 = (const float4*)h1;
        #pragma unroll
        for (int i = 0; i < 8; i++) {
            const int fidx = i * 256 + t;
            const int row = fidx >> 4;
            const int q = fidx & 15;
            const int n = nbase + row;
            float4 v = make_float4(0.f, 0.f, 0.f, 0.f);
            if (n < N_NODESC) {
                const float4 h = h4[(size_t)n * 16 + q];
                const int c = q * 4;
                v.x = fmaxf(fmaf(h.x, scl[c + 0], sft[c + 0]), 0.f);
                v.y = fmaxf(fmaf(h.y, scl[c + 1], sft[c + 1]), 0.f);
                v.z = fmaxf(fmaf(h.z, scl[c + 2], sft[c + 2]), 0.f);
                v.w = fmaxf(fmaf(h.w, scl[c + 3], sft[c + 3]), 0.f);
            }
            *(float4*)&lin[row][q * 4] = v;
        }
    }
    __syncthreads();

    const int g = t & 7;
    const int r0 = t >> 3;
    const float4* lW4 = (const float4*)lW;
    const float4* b4 = (const float4*)b2;
    const float4 bb0 = b4[g * 2 + 0];
    const float4 bb1 = b4[g * 2 + 1];
    float4 a00 = bb0, a01 = bb1, a10 = bb0, a11 = bb1;
    float4 a20 = bb0, a21 = bb1, a30 = bb0, a31 = bb1;
    for (int k = 0; k < 64; k++) {
        const float v0 = lin[r0][k];
        const float v1 = lin[r0 + 32][k];
        const float v2 = lin[r0 + 64][k];
        const float v3 = lin[r0 + 96][k];
        const float4 w0 = lW4[k * 16 + g * 2 + 0];
        const float4 w1 = lW4[k * 16 + g * 2 + 1];
        a00.x = fmaf(v0, w0.x, a00.x); a00.y = fmaf(v0, w0.y, a00.y);
        a00.z = fmaf(v0, w0.z, a00.z); a00.w = fmaf(v0, w0.w, a00.w);
        a01.x = fmaf(v0, w1.x, a01.x); a01.y = fmaf(v0, w1.y, a01.y);
        a01.z = fmaf(v0, w1.z, a01.z); a01.w = fmaf(v0, w1.w, a01.w);
        a10.x = fmaf(v1, w0.x, a10.x); a10.y = fmaf(v1, w0.y, a10.y);
        a10.z = fmaf(v1, w0.z, a10.z); a10.w = fmaf(v1, w0.w, a10.w);
        a11.x = fmaf(v1, w1.x, a11.x); a11.y = fmaf(v1, w1.y, a11.y);
        a11.z = fmaf(v1, w1.z, a11.z); a11.w = fmaf(v1, w1.w, a11.w);
        a20.x = fmaf(v2, w0.x, a20.x); a20.y = fmaf(v2, w0.y, a20.y);
        a20.z = fmaf(v2, w0.z, a20.z); a20.w = fmaf(v2, w0.w, a20.w);
        a21.x = fmaf(v2, w1.x, a21.x); a21.y = fmaf(v2, w1.y, a21.y);
        a21.z = fmaf(v2, w1.z, a21.z); a21.w = fmaf(v2, w1.w, a21.w);
        a30.x = fmaf(v3, w0.x, a30.x); a30.y = fmaf(v3, w0.y, a30.y);
        a30.z = fmaf(v3, w0.z, a30.z); a30.w = fmaf(v3, w0.w, a30.w);
        a31.x = fmaf(v3, w1.x, a31.x); a31.y = fmaf(v3, w1.y, a31.y);
        a31.z = fmaf(v3, w1.z, a31.z); a31.w = fmaf(v3, w1.w, a31.w);
    }
    const float4 A0[4] = {a00, a10, a20, a30};
    const float4 A1[4] = {a01, a11, a21, a31};
    float4* o4 = (float4*)out;
    #pragma unroll
    for (int j = 0; j < 4; j++) {
        const int n = nbase + r0 + 32 * j;
        if (n < N_NODESC) {
            o4[(size_t)n * 16 + g * 2 + 0] = A0[j];
            o4[(size_t)n * 16 + g * 2 + 1] = A1[j];
        }
    }
}

// ---------------------------------------------------------------------------
extern "C" void kernel_launch(void* const* d_in, const int* in_sizes, int n_in,
                              void* d_out, int out_size, void* d_ws, size_t ws_size,
                              hipStream_t stream) {
    const float* x     = (const float*)d_in[0];
    const float* emb   = (const float*)d_in[1];
    const float* eps   = (const float*)d_in[2];
    const float* W1    = (const float*)d_in[3];
    const float* b1    = (const float*)d_in[4];
    const float* gamma = (const float*)d_in[5];
    const float* beta  = (const float*)d_in[6];
    const float* W2    = (const float*)d_in[7];
    const float* b2    = (const float*)d_in[8];
    const int*   ei    = (const int*)d_in[9];
    const int*   ea    = (const int*)d_in[10];
    float* out = (float*)d_out;

    // ws: [cs 64][css 64][gcur NBUCK][tmp NBUCK*BCAPG][xh N*64 bf16]  (~22 MB)
    float* ws    = (float*)d_ws;
    float* cs    = ws;
    float* css   = ws + 64;
    int*   gcur  = (int*)(ws + 128);
    int*   tmp   = gcur + NBUCK;
    ushort* xh   = (ushort*)(tmp + (size_t)NBUCK * BCAPG);

    // zero cs/css/gcur (4.6 KB)
    hipMemsetAsync(d_ws, 0, (size_t)(128 + NBUCK) * sizeof(int), stream);

    k_castsort<<<SBLK, 1024, 0, stream>>>(ei, ea, x, (uint2*)xh, gcur, tmp);
    k_aggmlp1<<<NUSED, 512, 0, stream>>>(xh, emb, x, eps, gcur, tmp,
                                         W1, b1, out, cs, css);   // h1 -> d_out
    k_mlp2<<<NUSED, 256, 0, stream>>>(out, W2, b2, gamma, beta, cs, css, out);
}

// Round 9
// 199.838 us; speedup vs baseline: 6.1428x; 1.0247x over previous
//
#include <hip/hip_runtime.h>

#define N_NODESC 100000
#define N_EDGESC 1600000
#define BN_EPSC 1e-5f
#define NBUCK 1024              // coarse buckets (dst>>7, 128 nodes each), 782 used
#define NUSED 782               // ceil(100000/128)
#define SBLK 256                // castsort blocks
#define EPB (N_EDGESC / SBLK)   // 6250 edges per block
#define MT 128                  // nodes per MLP block
#define BCAPG 2304              // global per-bucket stride (mean 1562, ~18 sigma)
#define NSPREAD 16              // BN-stat atomic spreading (Guideline 12)

// ---------------------------------------------------------------------------
// K_castsort: ONE preprocessing kernel.  (R2 verbatim — proven)
// packed = src(17b) | attr<<17(2b) | (dst&127)<<19(7b).
// ---------------------------------------------------------------------------
__global__ __launch_bounds__(1024) void k_castsort(
    const int* __restrict__ ei, const int* __restrict__ ea,
    const float* __restrict__ x, uint2* __restrict__ xh4,
    int* __restrict__ gcur, int* __restrict__ tmp)
{
    __shared__ int ledge[EPB + 22];     // 6272 sorted packed edges
    __shared__ int cnt[NBUCK];
    __shared__ int cstart[NBUCK + 1];
    __shared__ int cur[NBUCK];
    __shared__ int gofs[NBUCK];
    __shared__ int wtot[16];
    const int t = threadIdx.x;
    const int k = blockIdx.x;

    cnt[t] = 0;
    {   // ---- bf16 cast, batched ----
        const float4* x4 = (const float4*)x;
        const int g = k * 1024 + t;
        float4 v[7];
        bool m[7];
        #pragma unroll
        for (int i = 0; i < 7; i++) {
            const int idx = g + i * (SBLK * 1024);
            m[i] = (idx < N_NODESC * 16);
            if (m[i]) v[i] = x4[idx];
        }
        #pragma unroll
        for (int i = 0; i < 7; i++) {
            if (m[i]) {
                const int idx = g + i * (SBLK * 1024);
                unsigned int a = __float_as_uint(v[i].x);
                unsigned int b = __float_as_uint(v[i].y);
                unsigned int c = __float_as_uint(v[i].z);
                unsigned int d = __float_as_uint(v[i].w);
                a = (a + 0x7FFFu + ((a >> 16) & 1u)) >> 16;
                b = (b + 0x7FFFu + ((b >> 16) & 1u)) >> 16;
                c = (c + 0x7FFFu + ((c >> 16) & 1u)) >> 16;
                d = (d + 0x7FFFu + ((d >> 16) & 1u)) >> 16;
                xh4[idx] = make_uint2(a | (b << 16), c | (d << 16));
            }
        }
    }
    __syncthreads();        // cnt zeroed before counting

    int pk[7], bk[7];
    const int base = k * EPB;
    #pragma unroll
    for (int i = 0; i < 7; i++) {
        const int e = base + i * 1024 + t;
        if (e < base + EPB) {
            const int src = ei[e];
            const int dst = ei[N_EDGESC + e];
            const int a = ea[e];
            pk[i] = src | (a << 17) | ((dst & 127) << 19);
            bk[i] = dst >> 7;
            atomicAdd(&cnt[bk[i]], 1);
        } else bk[i] = -1;
    }
    __syncthreads();

    {   // exclusive scan of 1024 counts
        const int lane = t & 63;
        const int w = t >> 6;
        const int v = cnt[t];
        int inc = v;
        #pragma unroll
        for (int d = 1; d < 64; d <<= 1) {
            const int u = __shfl_up(inc, d);
            if (lane >= d) inc += u;
        }
        if (lane == 63) wtot[w] = inc;
        __syncthreads();
        int add = 0;
        #pragma unroll
        for (int w2 = 0; w2 < 16; w2++) if (w2 < w) add += wtot[w2];
        const int ex = inc - v + add;
        cstart[t] = ex;
        cur[t] = ex;
        if (t == 1023) cstart[NBUCK] = ex + v;
    }
    __syncthreads();

    #pragma unroll
    for (int i = 0; i < 7; i++) {
        if (bk[i] >= 0) {
            const int pos = atomicAdd(&cur[bk[i]], 1);
            ledge[pos] = pk[i];
        }
    }
    {
        const int c = cnt[t];
        if (c > 0) gofs[t] = atomicAdd(&gcur[t], c);
    }
    __syncthreads();

    for (int i = t; i < EPB; i += 1024) {
        int lo = 0, hi = NBUCK;
        #pragma unroll
        for (int s = 0; s < 10; s++) {
            const int mid = (lo + hi) >> 1;
            if (cstart[mid] <= i) lo = mid; else hi = mid;
        }
        const int o = gofs[lo] + (i - cstart[lo]);
        if (o < BCAPG) tmp[lo * BCAPG + o] = ledge[i];
    }
}

// ---------------------------------------------------------------------------
// K_aggmlp1 (R8 structure, one change): BN-stat atomics spread 16x.
//  Theory: 128 atomics/block x 782 blocks into a 512B region = 100k fp32
//  atomics on 8 cache lines in one XCD's L2 — a 20-40us serialized drain
//  that gated both mlp1-R2 (43.9us @ ~5us compute, occ 14%) and this
//  kernel's ~25us excess over the 43.4us gather floor.  Block b now adds
//  into slice (b & 15) of cs/css[16][64]; contention per address 782 -> ~49.
// ---------------------------------------------------------------------------
__global__ __launch_bounds__(512) void k_aggmlp1(
    const ushort* __restrict__ xh, const float* __restrict__ emb,
    const float* __restrict__ x, const float* __restrict__ epsp,
    const int* __restrict__ gcur, const int* __restrict__ tmp,
    const float* __restrict__ W1, const float* __restrict__ b1,
    float* __restrict__ out, float* __restrict__ cs, float* __restrict__ css)
{
    __shared__ int packedL[BCAPG];      // 9216B; aliased by redS/redQ at end
    __shared__ float lin[MT][68];       // 34816B
    __shared__ float lW[4096];          // 16384B
    __shared__ int cnt[128];
    __shared__ int cst[128];
    __shared__ int cur[128];
    __shared__ float emL[4][68];        // padded: rows 68 words apart
    const int t = threadIdx.x;
    const int b = blockIdx.x;
    const int start = b * BCAPG;

    {   // ---- stage W1 early: latency hides under the whole sort phase ---
        const float4* W4 = (const float4*)W1;
        float4* lW4s = (float4*)lW;
        lW4s[t] = W4[t];
        lW4s[512 + t] = W4[512 + t];
    }
    int cntb = gcur[b];
    if (cntb > BCAPG) cntb = BCAPG;
    if (t < 128) cnt[t] = 0;
    if (t < 256) emL[t >> 6][t & 63] = emb[t];
    __syncthreads();

    // pass 1: per-node counts
    for (int e = t; e < cntb; e += 512)
        atomicAdd(&cnt[(tmp[start + e] >> 19) & 127], 1);
    __syncthreads();
    if (t < 64) {   // scan 128 counts (two 64-lane halves)
        const int lane = t;
        const int v0 = cnt[lane];
        const int v1 = cnt[64 + lane];
        int i0 = v0, i1 = v1;
        #pragma unroll
        for (int d = 1; d < 64; d <<= 1) {
            const int u0 = __shfl_up(i0, d);
            const int u1 = __shfl_up(i1, d);
            if (lane >= d) { i0 += u0; i1 += u1; }
        }
        const int tot0 = __shfl(i0, 63);
        cst[lane] = i0 - v0;
        cst[64 + lane] = tot0 + i1 - v1;
        cur[lane] = i0 - v0;
        cur[64 + lane] = tot0 + i1 - v1;
    }
    __syncthreads();
    // pass 2: place node-sorted into LDS
    for (int e = t; e < cntb; e += 512) {
        const int p = tmp[start + e];
        const int pos = atomicAdd(&cur[(p >> 19) & 127], 1);
        if (pos < BCAPG) packedL[pos] = p;
    }
    __syncthreads();

    // ---- phase A: aggregate; group g -> nodes g*2,g*2+1; lane q = octet -
    {
        const int g = t >> 3;
        const int q = t & 7;                 // floats [q*8, q*8+8)
        const float sc1 = 1.0f + epsp[0];
        const uint4* xv8 = (const uint4*)xh; // 16B = 8 bf16 per lane
        const float4* x4 = (const float4*)x;
        const float* eq = &emL[0][0] + q * 8;
        for (int j = 0; j < 2; j++) {
            const int nl = g * 2 + j;
            const int n = b * 128 + nl;
            int e = cst[nl];
            const int ee = cur[nl];           // cur == end after pass 2
            float4 aL = make_float4(0.f, 0.f, 0.f, 0.f);
            float4 aH = make_float4(0.f, 0.f, 0.f, 0.f);
            if (n < N_NODESC) {
                const float4 v0 = x4[(size_t)n * 16 + q * 2];
                const float4 v1 = x4[(size_t)n * 16 + q * 2 + 1];
                aL.x = sc1 * v0.x; aL.y = sc1 * v0.y;
                aL.z = sc1 * v0.z; aL.w = sc1 * v0.w;
                aH.x = sc1 * v1.x; aH.y = sc1 * v1.y;
                aH.z = sc1 * v1.z; aH.w = sc1 * v1.w;
            }
            for (; e + 2 <= ee; e += 2) {
                const int p0 = packedL[e];
                const int p1 = packedL[e + 1];
                const uint4 u0 = xv8[(size_t)(p0 & 0x1FFFF) * 8 + q];
                const uint4 u1 = xv8[(size_t)(p1 & 0x1FFFF) * 8 + q];
                const float* e0 = eq + ((p0 >> 17) & 3) * 68;
                const float* e1 = eq + ((p1 >> 17) & 3) * 68;
                const float4 t0L = *(const float4*)(e0);
                const float4 t0H = *(const float4*)(e0 + 4);
                const float4 t1L = *(const float4*)(e1);
                const float4 t1H = *(const float4*)(e1 + 4);
                aL.x += fmaxf(__uint_as_float(u0.x << 16)          + t0L.x, 0.f)
                      + fmaxf(__uint_as_float(u1.x << 16)          + t1L.x, 0.f);
                aL.y += fmaxf(__uint_as_float(u0.x & 0xFFFF0000u)  + t0L.y, 0.f)
                      + fmaxf(__uint_as_float(u1.x & 0xFFFF0000u)  + t1L.y, 0.f);
                aL.z += fmaxf(__uint_as_float(u0.y << 16)          + t0L.z, 0.f)
                      + fmaxf(__uint_as_float(u1.y << 16)          + t1L.z, 0.f);
                aL.w += fmaxf(__uint_as_float(u0.y & 0xFFFF0000u)  + t0L.w, 0.f)
                      + fmaxf(__uint_as_float(u1.y & 0xFFFF0000u)  + t1L.w, 0.f);
                aH.x += fmaxf(__uint_as_float(u0.z << 16)          + t0H.x, 0.f)
                      + fmaxf(__uint_as_float(u1.z << 16)          + t1H.x, 0.f);
                aH.y += fmaxf(__uint_as_float(u0.z & 0xFFFF0000u)  + t0H.y, 0.f)
                      + fmaxf(__uint_as_float(u1.z & 0xFFFF0000u)  + t1H.y, 0.f);
                aH.z += fmaxf(__uint_as_float(u0.w << 16)          + t0H.z, 0.f)
                      + fmaxf(__uint_as_float(u1.w << 16)          + t1H.z, 0.f);
                aH.w += fmaxf(__uint_as_float(u0.w & 0xFFFF0000u)  + t0H.w, 0.f)
                      + fmaxf(__uint_as_float(u1.w & 0xFFFF0000u)  + t1H.w, 0.f);
            }
            for (; e < ee; e++) {
                const int p0 = packedL[e];
                const uint4 u0 = xv8[(size_t)(p0 & 0x1FFFF) * 8 + q];
                const float* e0 = eq + ((p0 >> 17) & 3) * 68;
                const float4 t0L = *(const float4*)(e0);
                const float4 t0H = *(const float4*)(e0 + 4);
                aL.x += fmaxf(__uint_as_float(u0.x << 16)         + t0L.x, 0.f);
                aL.y += fmaxf(__uint_as_float(u0.x & 0xFFFF0000u) + t0L.y, 0.f);
                aL.z += fmaxf(__uint_as_float(u0.y << 16)         + t0L.z, 0.f);
                aL.w += fmaxf(__uint_as_float(u0.y & 0xFFFF0000u) + t0L.w, 0.f);
                aH.x += fmaxf(__uint_as_float(u0.z << 16)         + t0H.x, 0.f);
                aH.y += fmaxf(__uint_as_float(u0.z & 0xFFFF0000u) + t0H.y, 0.f);
                aH.z += fmaxf(__uint_as_float(u0.w << 16)         + t0H.z, 0.f);
                aH.w += fmaxf(__uint_as_float(u0.w & 0xFFFF0000u) + t0H.w, 0.f);
            }
            // h_pre -> LDS tile (own cells only; no cross-thread hazard)
            *(float4*)&lin[nl][q * 8]     = aL;
            *(float4*)&lin[nl][q * 8 + 4] = aH;
        }
    }
    __syncthreads();    // lin complete + lW visible

    // ---- phase B: h1 = lin @ W1 + b1 ; store; BN sums -------------------
    const int gc = t & 7;          // col group: cols [gc*8, gc*8+8)
    const int r0 = t >> 3;         // rows r0, r0+64
    const float4* lW4 = (const float4*)lW;
    const float4* b4 = (const float4*)b1;
    const float4 bb0 = b4[gc * 2 + 0];
    const float4 bb1 = b4[gc * 2 + 1];
    float4 a00 = bb0, a01 = bb1;   // row r0
    float4 a10 = bb0, a11 = bb1;   // row r0+64
    for (int k = 0; k < 64; k += 2) {
        const float v0a = lin[r0][k];
        const float v0b = lin[r0][k + 1];
        const float v1a = lin[r0 + 64][k];
        const float v1b = lin[r0 + 64][k + 1];
        const float4 w0a = lW4[k * 16 + gc * 2 + 0];
        const float4 w1a = lW4[k * 16 + gc * 2 + 1];
        const float4 w0b = lW4[(k + 1) * 16 + gc * 2 + 0];
        const float4 w1b = lW4[(k + 1) * 16 + gc * 2 + 1];
        a00.x = fmaf(v0a, w0a.x, a00.x); a00.y = fmaf(v0a, w0a.y, a00.y);
        a00.z = fmaf(v0a, w0a.z, a00.z); a00.w = fmaf(v0a, w0a.w, a00.w);
        a01.x = fmaf(v0a, w1a.x, a01.x); a01.y = fmaf(v0a, w1a.y, a01.y);
        a01.z = fmaf(v0a, w1a.z, a01.z); a01.w = fmaf(v0a, w1a.w, a01.w);
        a10.x = fmaf(v1a, w0a.x, a10.x); a10.y = fmaf(v1a, w0a.y, a10.y);
        a10.z = fmaf(v1a, w0a.z, a10.z); a10.w = fmaf(v1a, w0a.w, a10.w);
        a11.x = fmaf(v1a, w1a.x, a11.x); a11.y = fmaf(v1a, w1a.y, a11.y);
        a11.z = fmaf(v1a, w1a.z, a11.z); a11.w = fmaf(v1a, w1a.w, a11.w);
        a00.x = fmaf(v0b, w0b.x, a00.x); a00.y = fmaf(v0b, w0b.y, a00.y);
        a00.z = fmaf(v0b, w0b.z, a00.z); a00.w = fmaf(v0b, w0b.w, a00.w);
        a01.x = fmaf(v0b, w1b.x, a01.x); a01.y = fmaf(v0b, w1b.y, a01.y);
        a01.z = fmaf(v0b, w1b.z, a01.z); a01.w = fmaf(v0b, w1b.w, a01.w);
        a10.x = fmaf(v1b, w0b.x, a10.x); a10.y = fmaf(v1b, w0b.y, a10.y);
        a10.z = fmaf(v1b, w0b.z, a10.z); a10.w = fmaf(v1b, w0b.w, a10.w);
        a11.x = fmaf(v1b, w1b.x, a11.x); a11.y = fmaf(v1b, w1b.y, a11.y);
        a11.z = fmaf(v1b, w1b.z, a11.z); a11.w = fmaf(v1b, w1b.w, a11.w);
    }
    const int n0 = b * MT + r0;
    const int n1 = n0 + 64;
    const float msk0 = (n0 < N_NODESC) ? 1.0f : 0.0f;
    const float msk1 = (n1 < N_NODESC) ? 1.0f : 0.0f;
    float4* o4 = (float4*)out;
    if (n0 < N_NODESC) {
        o4[(size_t)n0 * 16 + gc * 2 + 0] = a00;
        o4[(size_t)n0 * 16 + gc * 2 + 1] = a01;
    }
    if (n1 < N_NODESC) {
        o4[(size_t)n1 * 16 + gc * 2 + 0] = a10;
        o4[(size_t)n1 * 16 + gc * 2 + 1] = a11;
    }

    float vs[8], vq[8];
    {
        const float e0[8] = {a00.x, a00.y, a00.z, a00.w,
                             a01.x, a01.y, a01.z, a01.w};
        const float e1[8] = {a10.x, a10.y, a10.z, a10.w,
                             a11.x, a11.y, a11.z, a11.w};
        #pragma unroll
        for (int c = 0; c < 8; c++) {
            const float v0 = e0[c] * msk0;
            const float v1 = e1[c] * msk1;
            vs[c] = v0 + v1;
            vq[c] = v0 * e0[c] + v1 * e1[c];
        }
    }
    #pragma unroll
    for (int o = 8; o < 64; o <<= 1) {
        #pragma unroll
        for (int c = 0; c < 8; c++) {
            vs[c] += __shfl_xor(vs[c], o);
            vq[c] += __shfl_xor(vq[c], o);
        }
    }
    __syncthreads();    // all lin reads done before redS/redQ alias packedL
    float* redS = (float*)packedL;          // [8][64]
    float* redQ = redS + 512;
    const int lane = t & 63;
    const int w = t >> 6;
    if (lane < 8) {     // lane==gc for these lanes
        #pragma unroll
        for (int c = 0; c < 8; c++) {
            redS[w * 64 + lane * 8 + c] = vs[c];
            redQ[w * 64 + lane * 8 + c] = vq[c];
        }
    }
    __syncthreads();
    if (t < 64) {
        float s = 0.f, qq = 0.f;
        #pragma unroll
        for (int w2 = 0; w2 < 8; w2++) {
            s  += redS[w2 * 64 + t];
            qq += redQ[w2 * 64 + t];
        }
        const int sl = (b & (NSPREAD - 1)) * 64;    // spread slice
        unsafeAtomicAdd(&cs[sl + t], s);
        unsafeAtomicAdd(&css[sl + t], qq);
    }
}

// ---------------------------------------------------------------------------
// K_mlp2 (R2 128-row structure): out = relu(BN(h1)) @ W2 + b2.
//  scl/sft now sum the 16 spread slices of cs/css.
// ---------------------------------------------------------------------------
__global__ __launch_bounds__(256) void k_mlp2(
    const float* h1, const float* __restrict__ W2, const float* __restrict__ b2,
    const float* __restrict__ gamma, const float* __restrict__ beta,
    const float* __restrict__ cs, const float* __restrict__ css,
    float* out)
{
    __shared__ float lin[MT][68];
    __shared__ float lW[4096];
    __shared__ float scl[64];
    __shared__ float sft[64];
    const int t = threadIdx.x;
    const int nbase = blockIdx.x * MT;

    if (t < 64) {
        float s = 0.f, qq = 0.f;
        #pragma unroll
        for (int i = 0; i < NSPREAD; i++) {
            s  += cs[i * 64 + t];
            qq += css[i * 64 + t];
        }
        const float inv = 1.0f / (float)N_NODESC;
        const float mu = s * inv;
        const float var = qq * inv - mu * mu;
        const float rs = rsqrtf(var + BN_EPSC);
        const float sc = rs * gamma[t];
        scl[t] = sc;
        sft[t] = fmaf(-mu, sc, beta[t]);
    }
    {
        const float4* W4 = (const float4*)W2;
        float4* lW4 = (float4*)lW;
        #pragma unroll
        for (int i = 0; i < 4; i++) lW4[i * 256 + t] = W4[i * 256 + t];
    }
    __syncthreads();
    {
        const float4* h4 = (const float4*)h1;
        #pragma unroll
        for (int i = 0; i < 8; i++) {
            const int fidx = i * 256 + t;
            const int row = fidx >> 4;
            const int q = fidx & 15;
            const int n = nbase + row;
            float4 v = make_float4(0.f, 0.f, 0.f, 0.f);
            if (n < N_NODESC) {
                const float4 h = h4[(size_t)n * 16 + q];
                const int c = q * 4;
                v.x = fmaxf(fmaf(h.x, scl[c + 0], sft[c + 0]), 0.f);
                v.y = fmaxf(fmaf(h.y, scl[c + 1], sft[c + 1]), 0.f);
                v.z = fmaxf(fmaf(h.z, scl[c + 2], sft[c + 2]), 0.f);
                v.w = fmaxf(fmaf(h.w, scl[c + 3], sft[c + 3]), 0.f);
            }
            *(float4*)&lin[row][q * 4] = v;
        }
    }
    __syncthreads();

    const int g = t & 7;
    const int r0 = t >> 3;
    const float4* lW4 = (const float4*)lW;
    const float4* b4 = (const float4*)b2;
    const float4 bb0 = b4[g * 2 + 0];
    const float4 bb1 = b4[g * 2 + 1];
    float4 a00 = bb0, a01 = bb1, a10 = bb0, a11 = bb1;
    float4 a20 = bb0, a21 = bb1, a30 = bb0, a31 = bb1;
    for (int k = 0; k < 64; k++) {
        const float v0 = lin[r0][k];
        const float v1 = lin[r0 + 32][k];
        const float v2 = lin[r0 + 64][k];
        const float v3 = lin[r0 + 96][k];
        const float4 w0 = lW4[k * 16 + g * 2 + 0];
        const float4 w1 = lW4[k * 16 + g * 2 + 1];
        a00.x = fmaf(v0, w0.x, a00.x); a00.y = fmaf(v0, w0.y, a00.y);
        a00.z = fmaf(v0, w0.z, a00.z); a00.w = fmaf(v0, w0.w, a00.w);
        a01.x = fmaf(v0, w1.x, a01.x); a01.y = fmaf(v0, w1.y, a01.y);
        a01.z = fmaf(v0, w1.z, a01.z); a01.w = fmaf(v0, w1.w, a01.w);
        a10.x = fmaf(v1, w0.x, a10.x); a10.y = fmaf(v1, w0.y, a10.y);
        a10.z = fmaf(v1, w0.z, a10.z); a10.w = fmaf(v1, w0.w, a10.w);
        a11.x = fmaf(v1, w1.x, a11.x); a11.y = fmaf(v1, w1.y, a11.y);
        a11.z = fmaf(v1, w1.z, a11.z); a11.w = fmaf(v1, w1.w, a11.w);
        a20.x = fmaf(v2, w0.x, a20.x); a20.y = fmaf(v2, w0.y, a20.y);
        a20.z = fmaf(v2, w0.z, a20.z); a20.w = fmaf(v2, w0.w, a20.w);
        a21.x = fmaf(v2, w1.x, a21.x); a21.y = fmaf(v2, w1.y, a21.y);
        a21.z = fmaf(v2, w1.z, a21.z); a21.w = fmaf(v2, w1.w, a21.w);
        a30.x = fmaf(v3, w0.x, a30.x); a30.y = fmaf(v3, w0.y, a30.y);
        a30.z = fmaf(v3, w0.z, a30.z); a30.w = fmaf(v3, w0.w, a30.w);
        a31.x = fmaf(v3, w1.x, a31.x); a31.y = fmaf(v3, w1.y, a31.y);
        a31.z = fmaf(v3, w1.z, a31.z); a31.w = fmaf(v3, w1.w, a31.w);
    }
    const float4 A0[4] = {a00, a10, a20, a30};
    const float4 A1[4] = {a01, a11, a21, a31};
    float4* o4 = (float4*)out;
    #pragma unroll
    for (int j = 0; j < 4; j++) {
        const int n = nbase + r0 + 32 * j;
        if (n < N_NODESC) {
            o4[(size_t)n * 16 + g * 2 + 0] = A0[j];
            o4[(size_t)n * 16 + g * 2 + 1] = A1[j];
        }
    }
}

// ---------------------------------------------------------------------------
extern "C" void kernel_launch(void* const* d_in, const int* in_sizes, int n_in,
                              void* d_out, int out_size, void* d_ws, size_t ws_size,
                              hipStream_t stream) {
    const float* x     = (const float*)d_in[0];
    const float* emb   = (const float*)d_in[1];
    const float* eps   = (const float*)d_in[2];
    const float* W1    = (const float*)d_in[3];
    const float* b1    = (const float*)d_in[4];
    const float* gamma = (const float*)d_in[5];
    const float* beta  = (const float*)d_in[6];
    const float* W2    = (const float*)d_in[7];
    const float* b2    = (const float*)d_in[8];
    const int*   ei    = (const int*)d_in[9];
    const int*   ea    = (const int*)d_in[10];
    float* out = (float*)d_out;

    // ws: [cs 16x64][css 16x64][gcur NBUCK][tmp NBUCK*BCAPG][xh N*64 bf16]
    float* ws    = (float*)d_ws;
    float* cs    = ws;                      // [NSPREAD][64]
    float* css   = ws + NSPREAD * 64;       // [NSPREAD][64]
    int*   gcur  = (int*)(ws + 2 * NSPREAD * 64);
    int*   tmp   = gcur + NBUCK;
    ushort* xh   = (ushort*)(tmp + (size_t)NBUCK * BCAPG);

    // zero cs/css slices + gcur (12.3 KB)
    hipMemsetAsync(d_ws, 0, (size_t)(2 * NSPREAD * 64 + NBUCK) * sizeof(int), stream);

    k_castsort<<<SBLK, 1024, 0, stream>>>(ei, ea, x, (uint2*)xh, gcur, tmp);
    k_aggmlp1<<<NUSED, 512, 0, stream>>>(xh, emb, x, eps, gcur, tmp,
                                         W1, b1, out, cs, css);   // h1 -> d_out
    k_mlp2<<<NUSED, 256, 0, stream>>>(out, W2, b2, gamma, beta, cs, css, out);
}

// Round 10
// 196.572 us; speedup vs baseline: 6.2449x; 1.0166x over previous
//
#include <hip/hip_runtime.h>

#define N_NODESC 100000
#define N_EDGESC 1600000
#define BN_EPSC 1e-5f
#define NBUCK 1024              // coarse buckets (dst>>7, 128 nodes each), 782 used
#define NUSED 782               // ceil(100000/128)
#define SBLK 256                // castsort blocks
#define EPB (N_EDGESC / SBLK)   // 6250 edges per block
#define MT 128                  // nodes per MLP block
#define BCAPG 2304              // global per-bucket stride (mean 1562, ~18 sigma)
#define NSPREAD 16              // BN-stat atomic spreading (Guideline 12)

// ---------------------------------------------------------------------------
// K_castsort: ONE preprocessing kernel.  (R2 verbatim — proven)
// packed = src(17b) | attr<<17(2b) | (dst&127)<<19(7b).
// ---------------------------------------------------------------------------
__global__ __launch_bounds__(1024) void k_castsort(
    const int* __restrict__ ei, const int* __restrict__ ea,
    const float* __restrict__ x, uint2* __restrict__ xh4,
    int* __restrict__ gcur, int* __restrict__ tmp)
{
    __shared__ int ledge[EPB + 22];     // 6272 sorted packed edges
    __shared__ int cnt[NBUCK];
    __shared__ int cstart[NBUCK + 1];
    __shared__ int cur[NBUCK];
    __shared__ int gofs[NBUCK];
    __shared__ int wtot[16];
    const int t = threadIdx.x;
    const int k = blockIdx.x;

    cnt[t] = 0;
    {   // ---- bf16 cast, batched ----
        const float4* x4 = (const float4*)x;
        const int g = k * 1024 + t;
        float4 v[7];
        bool m[7];
        #pragma unroll
        for (int i = 0; i < 7; i++) {
            const int idx = g + i * (SBLK * 1024);
            m[i] = (idx < N_NODESC * 16);
            if (m[i]) v[i] = x4[idx];
        }
        #pragma unroll
        for (int i = 0; i < 7; i++) {
            if (m[i]) {
                const int idx = g + i * (SBLK * 1024);
                unsigned int a = __float_as_uint(v[i].x);
                unsigned int b = __float_as_uint(v[i].y);
                unsigned int c = __float_as_uint(v[i].z);
                unsigned int d = __float_as_uint(v[i].w);
                a = (a + 0x7FFFu + ((a >> 16) & 1u)) >> 16;
                b = (b + 0x7FFFu + ((b >> 16) & 1u)) >> 16;
                c = (c + 0x7FFFu + ((c >> 16) & 1u)) >> 16;
                d = (d + 0x7FFFu + ((d >> 16) & 1u)) >> 16;
                xh4[idx] = make_uint2(a | (b << 16), c | (d << 16));
            }
        }
    }
    __syncthreads();        // cnt zeroed before counting

    int pk[7], bk[7];
    const int base = k * EPB;
    #pragma unroll
    for (int i = 0; i < 7; i++) {
        const int e = base + i * 1024 + t;
        if (e < base + EPB) {
            const int src = ei[e];
            const int dst = ei[N_EDGESC + e];
            const int a = ea[e];
            pk[i] = src | (a << 17) | ((dst & 127) << 19);
            bk[i] = dst >> 7;
            atomicAdd(&cnt[bk[i]], 1);
        } else bk[i] = -1;
    }
    __syncthreads();

    {   // exclusive scan of 1024 counts
        const int lane = t & 63;
        const int w = t >> 6;
        const int v = cnt[t];
        int inc = v;
        #pragma unroll
        for (int d = 1; d < 64; d <<= 1) {
            const int u = __shfl_up(inc, d);
            if (lane >= d) inc += u;
        }
        if (lane == 63) wtot[w] = inc;
        __syncthreads();
        int add = 0;
        #pragma unroll
        for (int w2 = 0; w2 < 16; w2++) if (w2 < w) add += wtot[w2];
        const int ex = inc - v + add;
        cstart[t] = ex;
        cur[t] = ex;
        if (t == 1023) cstart[NBUCK] = ex + v;
    }
    __syncthreads();

    #pragma unroll
    for (int i = 0; i < 7; i++) {
        if (bk[i] >= 0) {
            const int pos = atomicAdd(&cur[bk[i]], 1);
            ledge[pos] = pk[i];
        }
    }
    {
        const int c = cnt[t];
        if (c > 0) gofs[t] = atomicAdd(&gcur[t], c);
    }
    __syncthreads();

    for (int i = t; i < EPB; i += 1024) {
        int lo = 0, hi = NBUCK;
        #pragma unroll
        for (int s = 0; s < 10; s++) {
            const int mid = (lo + hi) >> 1;
            if (cstart[mid] <= i) lo = mid; else hi = mid;
        }
        const int o = gofs[lo] + (i - cstart[lo]);
        if (o < BCAPG) tmp[lo * BCAPG + o] = ledge[i];
    }
}

// ---------------------------------------------------------------------------
// K_aggmlp1 (R9 + dynamic node scheduling in phase A):
//  R9 diagnosis: the ~21us excess over the 43.4us gather floor is the
//  phase-A->B barrier waiting on the SLOWEST static group (max over 64
//  groups of Poisson(32) edge work ~ 1.5x mean; only 2 blocks/CU to fill
//  in).  Fix: groups claim nodes from an LDS work counter (leader lane
//  atomicAdd + __shfl broadcast) — fast groups absorb high-degree nodes.
//  Gather body, GEMM, BN path unchanged (regalloc-safe after R4-R6).
// ---------------------------------------------------------------------------
__global__ __launch_bounds__(512) void k_aggmlp1(
    const ushort* __restrict__ xh, const float* __restrict__ emb,
    const float* __restrict__ x, const float* __restrict__ epsp,
    const int* __restrict__ gcur, const int* __restrict__ tmp,
    const float* __restrict__ W1, const float* __restrict__ b1,
    float* __restrict__ out, float* __restrict__ cs, float* __restrict__ css)
{
    __shared__ int packedL[BCAPG];      // 9216B; aliased by redS/redQ at end
    __shared__ float lin[MT][68];       // 34816B
    __shared__ float lW[4096];          // 16384B
    __shared__ int cnt[128];
    __shared__ int cst[128];
    __shared__ int cur[128];
    __shared__ float emL[4][68];        // padded: rows 68 words apart
    __shared__ int nodeCtr;             // dynamic work counter
    const int t = threadIdx.x;
    const int b = blockIdx.x;
    const int start = b * BCAPG;

    {   // ---- stage W1 early: latency hides under the whole sort phase ---
        const float4* W4 = (const float4*)W1;
        float4* lW4s = (float4*)lW;
        lW4s[t] = W4[t];
        lW4s[512 + t] = W4[512 + t];
    }
    int cntb = gcur[b];
    if (cntb > BCAPG) cntb = BCAPG;
    if (t < 128) cnt[t] = 0;
    if (t < 256) emL[t >> 6][t & 63] = emb[t];
    if (t == 0) nodeCtr = 0;
    __syncthreads();

    // pass 1: per-node counts
    for (int e = t; e < cntb; e += 512)
        atomicAdd(&cnt[(tmp[start + e] >> 19) & 127], 1);
    __syncthreads();
    if (t < 64) {   // scan 128 counts (two 64-lane halves)
        const int lane = t;
        const int v0 = cnt[lane];
        const int v1 = cnt[64 + lane];
        int i0 = v0, i1 = v1;
        #pragma unroll
        for (int d = 1; d < 64; d <<= 1) {
            const int u0 = __shfl_up(i0, d);
            const int u1 = __shfl_up(i1, d);
            if (lane >= d) { i0 += u0; i1 += u1; }
        }
        const int tot0 = __shfl(i0, 63);
        cst[lane] = i0 - v0;
        cst[64 + lane] = tot0 + i1 - v1;
        cur[lane] = i0 - v0;
        cur[64 + lane] = tot0 + i1 - v1;
    }
    __syncthreads();
    // pass 2: place node-sorted into LDS
    for (int e = t; e < cntb; e += 512) {
        const int p = tmp[start + e];
        const int pos = atomicAdd(&cur[(p >> 19) & 127], 1);
        if (pos < BCAPG) packedL[pos] = p;
    }
    __syncthreads();

    // ---- phase A: aggregate; groups claim nodes dynamically -------------
    {
        const int lane = t & 63;
        const int q = t & 7;                 // floats [q*8, q*8+8)
        const float sc1 = 1.0f + epsp[0];
        const uint4* xv8 = (const uint4*)xh; // 16B = 8 bf16 per lane
        const float4* x4 = (const float4*)x;
        const float* eq = &emL[0][0] + q * 8;
        for (;;) {
            int nl;
            if (q == 0) nl = atomicAdd(&nodeCtr, 1);
            nl = __shfl(nl, lane & 56);      // broadcast from group leader
            if (nl >= MT) break;
            const int n = b * 128 + nl;
            int e = cst[nl];
            const int ee = cur[nl];           // cur == end after pass 2
            float4 aL = make_float4(0.f, 0.f, 0.f, 0.f);
            float4 aH = make_float4(0.f, 0.f, 0.f, 0.f);
            if (n < N_NODESC) {
                const float4 v0 = x4[(size_t)n * 16 + q * 2];
                const float4 v1 = x4[(size_t)n * 16 + q * 2 + 1];
                aL.x = sc1 * v0.x; aL.y = sc1 * v0.y;
                aL.z = sc1 * v0.z; aL.w = sc1 * v0.w;
                aH.x = sc1 * v1.x; aH.y = sc1 * v1.y;
                aH.z = sc1 * v1.z; aH.w = sc1 * v1.w;
            }
            for (; e + 2 <= ee; e += 2) {
                const int p0 = packedL[e];
                const int p1 = packedL[e + 1];
                const uint4 u0 = xv8[(size_t)(p0 & 0x1FFFF) * 8 + q];
                const uint4 u1 = xv8[(size_t)(p1 & 0x1FFFF) * 8 + q];
                const float* e0 = eq + ((p0 >> 17) & 3) * 68;
                const float* e1 = eq + ((p1 >> 17) & 3) * 68;
                const float4 t0L = *(const float4*)(e0);
                const float4 t0H = *(const float4*)(e0 + 4);
                const float4 t1L = *(const float4*)(e1);
                const float4 t1H = *(const float4*)(e1 + 4);
                aL.x += fmaxf(__uint_as_float(u0.x << 16)          + t0L.x, 0.f)
                      + fmaxf(__uint_as_float(u1.x << 16)          + t1L.x, 0.f);
                aL.y += fmaxf(__uint_as_float(u0.x & 0xFFFF0000u)  + t0L.y, 0.f)
                      + fmaxf(__uint_as_float(u1.x & 0xFFFF0000u)  + t1L.y, 0.f);
                aL.z += fmaxf(__uint_as_float(u0.y << 16)          + t0L.z, 0.f)
                      + fmaxf(__uint_as_float(u1.y << 16)          + t1L.z, 0.f);
                aL.w += fmaxf(__uint_as_float(u0.y & 0xFFFF0000u)  + t0L.w, 0.f)
                      + fmaxf(__uint_as_float(u1.y & 0xFFFF0000u)  + t1L.w, 0.f);
                aH.x += fmaxf(__uint_as_float(u0.z << 16)          + t0H.x, 0.f)
                      + fmaxf(__uint_as_float(u1.z << 16)          + t1H.x, 0.f);
                aH.y += fmaxf(__uint_as_float(u0.z & 0xFFFF0000u)  + t0H.y, 0.f)
                      + fmaxf(__uint_as_float(u1.z & 0xFFFF0000u)  + t1H.y, 0.f);
                aH.z += fmaxf(__uint_as_float(u0.w << 16)          + t0H.z, 0.f)
                      + fmaxf(__uint_as_float(u1.w << 16)          + t1H.z, 0.f);
                aH.w += fmaxf(__uint_as_float(u0.w & 0xFFFF0000u)  + t0H.w, 0.f)
                      + fmaxf(__uint_as_float(u1.w & 0xFFFF0000u)  + t1H.w, 0.f);
            }
            for (; e < ee; e++) {
                const int p0 = packedL[e];
                const uint4 u0 = xv8[(size_t)(p0 & 0x1FFFF) * 8 + q];
                const float* e0 = eq + ((p0 >> 17) & 3) * 68;
                const float4 t0L = *(const float4*)(e0);
                const float4 t0H = *(const float4*)(e0 + 4);
                aL.x += fmaxf(__uint_as_float(u0.x << 16)         + t0L.x, 0.f);
                aL.y += fmaxf(__uint_as_float(u0.x & 0xFFFF0000u) + t0L.y, 0.f);
                aL.z += fmaxf(__uint_as_float(u0.y << 16)         + t0L.z, 0.f);
                aL.w += fmaxf(__uint_as_float(u0.y & 0xFFFF0000u) + t0L.w, 0.f);
                aH.x += fmaxf(__uint_as_float(u0.z << 16)         + t0H.x, 0.f);
                aH.y += fmaxf(__uint_as_float(u0.z & 0xFFFF0000u) + t0H.y, 0.f);
                aH.z += fmaxf(__uint_as_float(u0.w << 16)         + t0H.z, 0.f);
                aH.w += fmaxf(__uint_as_float(u0.w & 0xFFFF0000u) + t0H.w, 0.f);
            }
            // h_pre -> LDS tile (own cells only; node claimed exactly once)
            *(float4*)&lin[nl][q * 8]     = aL;
            *(float4*)&lin[nl][q * 8 + 4] = aH;
        }
    }
    __syncthreads();    // lin complete + lW visible

    // ---- phase B: h1 = lin @ W1 + b1 ; store; BN sums -------------------
    const int gc = t & 7;          // col group: cols [gc*8, gc*8+8)
    const int r0 = t >> 3;         // rows r0, r0+64
    const float4* lW4 = (const float4*)lW;
    const float4* b4 = (const float4*)b1;
    const float4 bb0 = b4[gc * 2 + 0];
    const float4 bb1 = b4[gc * 2 + 1];
    float4 a00 = bb0, a01 = bb1;   // row r0
    float4 a10 = bb0, a11 = bb1;   // row r0+64
    for (int k = 0; k < 64; k += 2) {
        const float v0a = lin[r0][k];
        const float v0b = lin[r0][k + 1];
        const float v1a = lin[r0 + 64][k];
        const float v1b = lin[r0 + 64][k + 1];
        const float4 w0a = lW4[k * 16 + gc * 2 + 0];
        const float4 w1a = lW4[k * 16 + gc * 2 + 1];
        const float4 w0b = lW4[(k + 1) * 16 + gc * 2 + 0];
        const float4 w1b = lW4[(k + 1) * 16 + gc * 2 + 1];
        a00.x = fmaf(v0a, w0a.x, a00.x); a00.y = fmaf(v0a, w0a.y, a00.y);
        a00.z = fmaf(v0a, w0a.z, a00.z); a00.w = fmaf(v0a, w0a.w, a00.w);
        a01.x = fmaf(v0a, w1a.x, a01.x); a01.y = fmaf(v0a, w1a.y, a01.y);
        a01.z = fmaf(v0a, w1a.z, a01.z); a01.w = fmaf(v0a, w1a.w, a01.w);
        a10.x = fmaf(v1a, w0a.x, a10.x); a10.y = fmaf(v1a, w0a.y, a10.y);
        a10.z = fmaf(v1a, w0a.z, a10.z); a10.w = fmaf(v1a, w0a.w, a10.w);
        a11.x = fmaf(v1a, w1a.x, a11.x); a11.y = fmaf(v1a, w1a.y, a11.y);
        a11.z = fmaf(v1a, w1a.z, a11.z); a11.w = fmaf(v1a, w1a.w, a11.w);
        a00.x = fmaf(v0b, w0b.x, a00.x); a00.y = fmaf(v0b, w0b.y, a00.y);
        a00.z = fmaf(v0b, w0b.z, a00.z); a00.w = fmaf(v0b, w0b.w, a00.w);
        a01.x = fmaf(v0b, w1b.x, a01.x); a01.y = fmaf(v0b, w1b.y, a01.y);
        a01.z = fmaf(v0b, w1b.z, a01.z); a01.w = fmaf(v0b, w1b.w, a01.w);
        a10.x = fmaf(v1b, w0b.x, a10.x); a10.y = fmaf(v1b, w0b.y, a10.y);
        a10.z = fmaf(v1b, w0b.z, a10.z); a10.w = fmaf(v1b, w0b.w, a10.w);
        a11.x = fmaf(v1b, w1b.x, a11.x); a11.y = fmaf(v1b, w1b.y, a11.y);
        a11.z = fmaf(v1b, w1b.z, a11.z); a11.w = fmaf(v1b, w1b.w, a11.w);
    }
    const int n0 = b * MT + r0;
    const int n1 = n0 + 64;
    const float msk0 = (n0 < N_NODESC) ? 1.0f : 0.0f;
    const float msk1 = (n1 < N_NODESC) ? 1.0f : 0.0f;
    float4* o4 = (float4*)out;
    if (n0 < N_NODESC) {
        o4[(size_t)n0 * 16 + gc * 2 + 0] = a00;
        o4[(size_t)n0 * 16 + gc * 2 + 1] = a01;
    }
    if (n1 < N_NODESC) {
        o4[(size_t)n1 * 16 + gc * 2 + 0] = a10;
        o4[(size_t)n1 * 16 + gc * 2 + 1] = a11;
    }

    float vs[8], vq[8];
    {
        const float e0[8] = {a00.x, a00.y, a00.z, a00.w,
                             a01.x, a01.y, a01.z, a01.w};
        const float e1[8] = {a10.x, a10.y, a10.z, a10.w,
                             a11.x, a11.y, a11.z, a11.w};
        #pragma unroll
        for (int c = 0; c < 8; c++) {
            const float v0 = e0[c] * msk0;
            const float v1 = e1[c] * msk1;
            vs[c] = v0 + v1;
            vq[c] = v0 * e0[c] + v1 * e1[c];
        }
    }
    #pragma unroll
    for (int o = 8; o < 64; o <<= 1) {
        #pragma unroll
        for (int c = 0; c < 8; c++) {
            vs[c] += __shfl_xor(vs[c], o);
            vq[c] += __shfl_xor(vq[c], o);
        }
    }
    __syncthreads();    // all lin reads done before redS/redQ alias packedL
    float* redS = (float*)packedL;          // [8][64]
    float* redQ = redS + 512;
    const int lane = t & 63;
    const int w = t >> 6;
    if (lane < 8) {     // lane==gc for these lanes
        #pragma unroll
        for (int c = 0; c < 8; c++) {
            redS[w * 64 + lane * 8 + c] = vs[c];
            redQ[w * 64 + lane * 8 + c] = vq[c];
        }
    }
    __syncthreads();
    if (t < 64) {
        float s = 0.f, qq = 0.f;
        #pragma unroll
        for (int w2 = 0; w2 < 8; w2++) {
            s  += redS[w2 * 64 + t];
            qq += redQ[w2 * 64 + t];
        }
        const int sl = (b & (NSPREAD - 1)) * 64;    // spread slice
        unsafeAtomicAdd(&cs[sl + t], s);
        unsafeAtomicAdd(&css[sl + t], qq);
    }
}

// ---------------------------------------------------------------------------
// K_mlp2 (512 threads, 128-row tile): out = relu(BN(h1)) @ W2 + b2.
//  R7 lesson: shrinking the TILE regressed (fixed W-staging overhead).
//  This keeps the tile and doubles the waves: 2 rows x 8 cols/thread,
//  staging uses 512 threads, GEMM critical path per barrier halves;
//  51.9KB LDS -> 3 blocks/CU now carries 24 waves/CU (was 12).
// ---------------------------------------------------------------------------
__global__ __launch_bounds__(512) void k_mlp2(
    const float* h1, const float* __restrict__ W2, const float* __restrict__ b2,
    const float* __restrict__ gamma, const float* __restrict__ beta,
    const float* __restrict__ cs, const float* __restrict__ css,
    float* out)
{
    __shared__ float lin[MT][68];
    __shared__ float lW[4096];
    __shared__ float scl[64];
    __shared__ float sft[64];
    const int t = threadIdx.x;
    const int nbase = blockIdx.x * MT;

    if (t < 64) {
        float s = 0.f, qq = 0.f;
        #pragma unroll
        for (int i = 0; i < NSPREAD; i++) {
            s  += cs[i * 64 + t];
            qq += css[i * 64 + t];
        }
        const float inv = 1.0f / (float)N_NODESC;
        const float mu = s * inv;
        const float var = qq * inv - mu * mu;
        const float rs = rsqrtf(var + BN_EPSC);
        const float sc = rs * gamma[t];
        scl[t] = sc;
        sft[t] = fmaf(-mu, sc, beta[t]);
    }
    {
        const float4* W4 = (const float4*)W2;
        float4* lW4 = (float4*)lW;
        lW4[t] = W4[t];
        lW4[512 + t] = W4[512 + t];
    }
    __syncthreads();
    {
        const float4* h4 = (const float4*)h1;
        #pragma unroll
        for (int i = 0; i < 4; i++) {
            const int fidx = i * 512 + t;
            const int row = fidx >> 4;
            const int q = fidx & 15;
            const int n = nbase + row;
            float4 v = make_float4(0.f, 0.f, 0.f, 0.f);
            if (n < N_NODESC) {
                const float4 h = h4[(size_t)n * 16 + q];
                const int c = q * 4;
                v.x = fmaxf(fmaf(h.x, scl[c + 0], sft[c + 0]), 0.f);
                v.y = fmaxf(fmaf(h.y, scl[c + 1], sft[c + 1]), 0.f);
                v.z = fmaxf(fmaf(h.z, scl[c + 2], sft[c + 2]), 0.f);
                v.w = fmaxf(fmaf(h.w, scl[c + 3], sft[c + 3]), 0.f);
            }
            *(float4*)&lin[row][q * 4] = v;
        }
    }
    __syncthreads();

    const int g = t & 7;           // col group: cols [g*8, g*8+8)
    const int r0 = t >> 3;         // rows r0, r0+64
    const float4* lW4 = (const float4*)lW;
    const float4* b4 = (const float4*)b2;
    const float4 bb0 = b4[g * 2 + 0];
    const float4 bb1 = b4[g * 2 + 1];
    float4 a00 = bb0, a01 = bb1;
    float4 a10 = bb0, a11 = bb1;
    for (int k = 0; k < 64; k++) {
        const float v0 = lin[r0][k];
        const float v1 = lin[r0 + 64][k];
        const float4 w0 = lW4[k * 16 + g * 2 + 0];
        const float4 w1 = lW4[k * 16 + g * 2 + 1];
        a00.x = fmaf(v0, w0.x, a00.x); a00.y = fmaf(v0, w0.y, a00.y);
        a00.z = fmaf(v0, w0.z, a00.z); a00.w = fmaf(v0, w0.w, a00.w);
        a01.x = fmaf(v0, w1.x, a01.x); a01.y = fmaf(v0, w1.y, a01.y);
        a01.z = fmaf(v0, w1.z, a01.z); a01.w = fmaf(v0, w1.w, a01.w);
        a10.x = fmaf(v1, w0.x, a10.x); a10.y = fmaf(v1, w0.y, a10.y);
        a10.z = fmaf(v1, w0.z, a10.z); a10.w = fmaf(v1, w0.w, a10.w);
        a11.x = fmaf(v1, w1.x, a11.x); a11.y = fmaf(v1, w1.y, a11.y);
        a11.z = fmaf(v1, w1.z, a11.z); a11.w = fmaf(v1, w1.w, a11.w);
    }
    float4* o4 = (float4*)out;
    const int n0 = nbase + r0;
    const int n1 = n0 + 64;
    if (n0 < N_NODESC) {
        o4[(size_t)n0 * 16 + g * 2 + 0] = a00;
        o4[(size_t)n0 * 16 + g * 2 + 1] = a01;
    }
    if (n1 < N_NODESC) {
        o4[(size_t)n1 * 16 + g * 2 + 0] = a10;
        o4[(size_t)n1 * 16 + g * 2 + 1] = a11;
    }
}

// ---------------------------------------------------------------------------
extern "C" void kernel_launch(void* const* d_in, const int* in_sizes, int n_in,
                              void* d_out, int out_size, void* d_ws, size_t ws_size,
                              hipStream_t stream) {
    const float* x     = (const float*)d_in[0];
    const float* emb   = (const float*)d_in[1];
    const float* eps   = (const float*)d_in[2];
    const float* W1    = (const float*)d_in[3];
    const float* b1    = (const float*)d_in[4];
    const float* gamma = (const float*)d_in[5];
    const float* beta  = (const float*)d_in[6];
    const float* W2    = (const float*)d_in[7];
    const float* b2    = (const float*)d_in[8];
    const int*   ei    = (const int*)d_in[9];
    const int*   ea    = (const int*)d_in[10];
    float* out = (float*)d_out;

    // ws: [cs 16x64][css 16x64][gcur NBUCK][tmp NBUCK*BCAPG][xh N*64 bf16]
    float* ws    = (float*)d_ws;
    float* cs    = ws;                      // [NSPREAD][64]
    float* css   = ws + NSPREAD * 64;       // [NSPREAD][64]
    int*   gcur  = (int*)(ws + 2 * NSPREAD * 64);
    int*   tmp   = gcur + NBUCK;
    ushort* xh   = (ushort*)(tmp + (size_t)NBUCK * BCAPG);

    // zero cs/css slices + gcur (12.3 KB)
    hipMemsetAsync(d_ws, 0, (size_t)(2 * NSPREAD * 64 + NBUCK) * sizeof(int), stream);

    k_castsort<<<SBLK, 1024, 0, stream>>>(ei, ea, x, (uint2*)xh, gcur, tmp);
    k_aggmlp1<<<NUSED, 512, 0, stream>>>(xh, emb, x, eps, gcur, tmp,
                                         W1, b1, out, cs, css);   // h1 -> d_out
    k_mlp2<<<NUSED, 512, 0, stream>>>(out, W2, b2, gamma, beta, cs, css, out);
}